// Round 3
// baseline (1173.691 us; speedup 1.0000x reference)
//
#include <hip/hip_runtime.h>
#include <hip/hip_bf16.h>
#include <math.h>

#define BATCH 2
#define SEQ 4096
#define DMODEL 1024
#define NH 4
#define DHEAD 256
#define NCHUNK 128
#define ROWS (BATCH * SEQ) /* 8192 */

typedef short s8v __attribute__((ext_vector_type(8)));   /* 8 bf16 in 4 VGPRs */
typedef float f4v __attribute__((ext_vector_type(4)));

__device__ __forceinline__ float sigm(float x) { return 1.0f / (1.0f + expf(-x)); }
__device__ __forceinline__ float siluf(float x) { return x / (1.0f + expf(-x)); }
__device__ __forceinline__ unsigned short f2b(float f) {
  __hip_bfloat16 h = __float2bfloat16(f);
  return *(unsigned short*)&h;
}
__device__ __forceinline__ float b2f(unsigned short u) {
  __hip_bfloat16 h = *(__hip_bfloat16*)&u;
  return __bfloat162float(h);
}
__device__ __forceinline__ unsigned int pk2(float lo, float hi) {
  return (unsigned int)f2b(lo) | ((unsigned int)f2b(hi) << 16);
}

/* ================= device bodies for fused kernels ================= */

__device__ __forceinline__ void prep_body(
    const float* __restrict__ x, __hip_bfloat16* __restrict__ xb,
    const float* __restrict__ Wb, const float* __restrict__ Wid,
    const float* __restrict__ alpha_id, const float* __restrict__ bidp,
    float* __restrict__ beta, float* __restrict__ idsc, int row,
    float (*red)[8]) {
  const int t = threadIdx.x;
  const long base = (long)row * DMODEL + t * 4;
  float4 xv = *(const float4*)(x + base);
  {
    __hip_bfloat16 tmp[4] = {__float2bfloat16(xv.x), __float2bfloat16(xv.y),
                             __float2bfloat16(xv.z), __float2bfloat16(xv.w)};
    *(ushort4*)(xb + base) = *(ushort4*)tmp;
  }
  float xa[4] = {xv.x, xv.y, xv.z, xv.w};
  float ab[4] = {0, 0, 0, 0}, ai[4] = {0, 0, 0, 0};
#pragma unroll
  for (int i = 0; i < 4; ++i) {
    int k = t * 4 + i;
    float4 wb4 = *(const float4*)(Wb + k * 4);
    float4 wi4 = *(const float4*)(Wid + k * 4);
    ab[0] = fmaf(xa[i], wb4.x, ab[0]); ab[1] = fmaf(xa[i], wb4.y, ab[1]);
    ab[2] = fmaf(xa[i], wb4.z, ab[2]); ab[3] = fmaf(xa[i], wb4.w, ab[3]);
    ai[0] = fmaf(xa[i], wi4.x, ai[0]); ai[1] = fmaf(xa[i], wi4.y, ai[1]);
    ai[2] = fmaf(xa[i], wi4.z, ai[2]); ai[3] = fmaf(xa[i], wi4.w, ai[3]);
  }
#pragma unroll
  for (int m = 1; m < 64; m <<= 1) {
#pragma unroll
    for (int hh = 0; hh < 4; ++hh) {
      ab[hh] += __shfl_xor(ab[hh], m);
      ai[hh] += __shfl_xor(ai[hh], m);
    }
  }
  if ((t & 63) == 0) {
    int wv = t >> 6;
#pragma unroll
    for (int hh = 0; hh < 4; ++hh) {
      red[wv][hh] = ab[hh];
      red[wv][4 + hh] = ai[hh];
    }
  }
  __syncthreads();
  if (t < 8) {
    float s = red[0][t] + red[1][t] + red[2][t] + red[3][t];
    if (t < 4) {
      beta[(long)row * NH + t] = sigm(s);
    } else {
      int hh = t - 4;
      idsc[(long)row * NH + hh] = 0.06f + sigm(alpha_id[hh]) * sigm(s + bidp[hh]);
    }
  }
}

__device__ __forceinline__ void tcast_body(
    const float* __restrict__ W, __hip_bfloat16* __restrict__ Wt,
    int K, int N, int Ks, int bx, int by, float (*tile)[33]) {
  const int t = threadIdx.x;
  const int tx = t & 31, ty = t >> 5;
  const int kb = by * 32, nb = bx * 32;
#pragma unroll
  for (int r = 0; r < 4; ++r) {
    int kk = kb + ty + 8 * r;
    tile[ty + 8 * r][tx] = (kk < K) ? W[(long)kk * N + nb + tx] : 0.f;
  }
  __syncthreads();
#pragma unroll
  for (int r = 0; r < 4; ++r) {
    Wt[(long)(nb + ty + 8 * r) * Ks + kb + tx] = __float2bfloat16(tile[tx][ty + 8 * r]);
  }
}

__device__ __forceinline__ void firT_body(
    const float* __restrict__ fshort, const float* __restrict__ flong,
    float* __restrict__ fsT, float* __restrict__ flT, int j) {
  const int t = threadIdx.x;
  if (j < 31) {
#pragma unroll
    for (int i = 0; i < 4; ++i) {
      int c = t * 4 + i;
      flT[j * 1024 + c] = flong[c * 31 + j];
    }
  } else {
    int tp = j - 31;
#pragma unroll
    for (int i = 0; i < 4; ++i) {
      int c = t * 4 + i;
      fsT[tp * 1024 + c] = fshort[c * 3 + tp];
    }
  }
}

__device__ __forceinline__ void fir_body(
    const float* __restrict__ v, const float* __restrict__ fsT,
    const float* __restrict__ flT, float* __restrict__ fs, float* __restrict__ fl,
    int row) {
  const int l = row & (SEQ - 1);
  const int t = threadIdx.x;
  const int cb = t * 4;
  float4 accl = make_float4(0, 0, 0, 0);
  float4 accs = make_float4(0, 0, 0, 0);
  const float* vb = v + (long)(row - 30) * DMODEL + cb;
  if (l >= 30) {
#pragma unroll
    for (int j = 0; j < 31; ++j) {
      float4 w4 = *(const float4*)(flT + j * DMODEL + cb);
      float4 xv = *(const float4*)(vb + (long)j * DMODEL);
      accl.x = fmaf(w4.x, xv.x, accl.x);
      accl.y = fmaf(w4.y, xv.y, accl.y);
      accl.z = fmaf(w4.z, xv.z, accl.z);
      accl.w = fmaf(w4.w, xv.w, accl.w);
      if (j >= 28) {
        float4 s4 = *(const float4*)(fsT + (j - 28) * DMODEL + cb);
        accs.x = fmaf(s4.x, xv.x, accs.x);
        accs.y = fmaf(s4.y, xv.y, accs.y);
        accs.z = fmaf(s4.z, xv.z, accs.z);
        accs.w = fmaf(s4.w, xv.w, accs.w);
      }
    }
  } else {
    for (int j = 30 - l; j < 31; ++j) {
      float4 w4 = *(const float4*)(flT + j * DMODEL + cb);
      float4 xv = *(const float4*)(vb + (long)j * DMODEL);
      accl.x = fmaf(w4.x, xv.x, accl.x);
      accl.y = fmaf(w4.y, xv.y, accl.y);
      accl.z = fmaf(w4.z, xv.z, accl.z);
      accl.w = fmaf(w4.w, xv.w, accl.w);
      if (j >= 28) {
        float4 s4 = *(const float4*)(fsT + (j - 28) * DMODEL + cb);
        accs.x = fmaf(s4.x, xv.x, accs.x);
        accs.y = fmaf(s4.y, xv.y, accs.y);
        accs.z = fmaf(s4.z, xv.z, accs.z);
        accs.w = fmaf(s4.w, xv.w, accs.w);
      }
    }
  }
  *(float4*)(fs + (long)row * DMODEL + cb) = accs;
  *(float4*)(fl + (long)row * DMODEL + cb) = accl;
}

__device__ __forceinline__ void stats_body(
    const float* __restrict__ x, const float* __restrict__ fs,
    const float* __restrict__ fl, const float* __restrict__ dl,
    __hip_bfloat16* __restrict__ rinb, int row) {
  const int b = row >> 12;
  const int l = row & (SEQ - 1);
  const int t = threadIdx.x;
  float4 xv = *(const float4*)(x + (long)row * DMODEL + t * 4);
  {
    __hip_bfloat16 tmp[4] = {__float2bfloat16(xv.x), __float2bfloat16(xv.y),
                             __float2bfloat16(xv.z), __float2bfloat16(xv.w)};
    *(ushort4*)(rinb + (long)row * 1056 + t * 4) = *(ushort4*)tmp;
  }
  if (t < 8) rinb[(long)row * 1056 + 1048 + t] = __float2bfloat16(0.f);
  const int h = t >> 6;
  const int lane = t & 63;
  const long base = (long)row * DMODEL + h * DHEAD + lane * 4;
  const long dbase = ((long)(b * NH + h) * SEQ + l) * DHEAD + lane * 4;
  float4 a = *(const float4*)(fs + base);
  float4 bq = *(const float4*)(fl + base);
  float4 cq = *(const float4*)(dl + dbase);
  float s[6];
  s[0] = a.x + a.y + a.z + a.w;
  s[1] = a.x * a.x + a.y * a.y + a.z * a.z + a.w * a.w;
  s[2] = bq.x + bq.y + bq.z + bq.w;
  s[3] = bq.x * bq.x + bq.y * bq.y + bq.z * bq.z + bq.w * bq.w;
  s[4] = cq.x + cq.y + cq.z + cq.w;
  s[5] = cq.x * cq.x + cq.y * cq.y + cq.z * cq.z + cq.w * cq.w;
#pragma unroll
  for (int m = 1; m < 64; m <<= 1)
#pragma unroll
    for (int j = 0; j < 6; ++j) s[j] += __shfl_xor(s[j], m);
  if (lane == 0) {
    __hip_bfloat16* rb = rinb + (long)row * 1056 + 1024;
    float m0 = s[0] * (1.f / 256.f);
    float m1 = s[2] * (1.f / 256.f);
    float m2 = s[4] * (1.f / 256.f);
    rb[h] = __float2bfloat16(m0);
    rb[4 + h] = __float2bfloat16(sqrtf(fmaxf(s[1] * (1.f / 256.f) - m0 * m0, 0.f)));
    rb[8 + h] = __float2bfloat16(m1);
    rb[12 + h] = __float2bfloat16(sqrtf(fmaxf(s[3] * (1.f / 256.f) - m1 * m1, 0.f)));
    rb[16 + h] = __float2bfloat16(m2);
    rb[20 + h] = __float2bfloat16(sqrtf(fmaxf(s[5] * (1.f / 256.f) - m2 * m2, 0.f)));
  }
}

/* phaseB single-wave body: S[256][16] in accumulators; no barriers; St via
   wave-private LDS (lgkmcnt only); u2^T redistribution via ds_bpermute. */
__device__ __forceinline__ void phaseB_wave(
    const __hip_bfloat16* __restrict__ qpk, const __hip_bfloat16* __restrict__ wb,
    const __hip_bfloat16* __restrict__ kTb, const __hip_bfloat16* __restrict__ attnb,
    const float* __restrict__ u, float* __restrict__ delta,
    int bh, int d0, short* St, int lane) {
  const int ln15 = lane & 15;
  const int qw = (lane >> 4) & 3;

  const short* wbase = (const short*)wb + (long)bh * SEQ * 256;
  const short* qbase = (const short*)qpk + (long)bh * SEQ * 256;
  const short* kTbase = (const short*)kTb + (long)bh * NCHUNK * 8192;
  const short* atbase = (const short*)attnb + (long)bh * NCHUNK * 1024;
  const float* ubase = u + (long)bh * SEQ * 256;
  float* dbase = delta + (long)bh * SEQ * 256;

  f4v Sacc[16];
#pragma unroll
  for (int kt = 0; kt < 16; ++kt) Sacc[kt] = (f4v){0.f, 0.f, 0.f, 0.f};

  s8v wA[2][8], kA[16], atv[2];
  float uf[2][4];
  {
#pragma unroll
    for (int mt = 0; mt < 2; ++mt)
#pragma unroll
      for (int ks = 0; ks < 8; ++ks)
        wA[mt][ks] = *(const s8v*)(wbase + (long)(mt * 16 + ln15) * 256 + ks * 32 + qw * 8);
#pragma unroll
    for (int kt = 0; kt < 16; ++kt)
      kA[kt] = *(const s8v*)(kTbase + (kt * 16 + ln15) * 32 + qw * 8);
#pragma unroll
    for (int mt = 0; mt < 2; ++mt) {
      atv[mt] = *(const s8v*)(atbase + (mt * 16 + ln15) * 32 + qw * 8);
#pragma unroll
      for (int r = 0; r < 4; ++r)
        uf[mt][r] = ubase[(long)(mt * 16 + qw * 4 + r) * 256 + d0 + ln15];
    }
  }

  const int idx0 = (((qw & 1) * 2) * 16 + ln15) * 4;
  const int idx1 = (((qw & 1) * 2 + 1) * 16 + ln15) * 4;
  const bool hiHalf = (qw >= 2);

  for (int c = 0; c < NCHUNK; ++c) {
    const int l0 = c * 32;

    s8v qA[2][8];
#pragma unroll
    for (int mt = 0; mt < 2; ++mt)
#pragma unroll
      for (int ks = 0; ks < 8; ++ks)
        qA[mt][ks] = *(const s8v*)(qbase + (long)(l0 + mt * 16 + ln15) * 256 + ks * 32 + qw * 8);

    /* (1) pack S^T into wave-private LDS */
#pragma unroll
    for (int kt = 0; kt < 16; ++kt) {
      ushort4 pk;
      pk.x = f2b(Sacc[kt][0]); pk.y = f2b(Sacc[kt][1]);
      pk.z = f2b(Sacc[kt][2]); pk.w = f2b(Sacc[kt][3]);
      *(ushort4*)&St[ln15 * 264 + kt * 16 + qw * 4] = pk;
    }
    asm volatile("s_waitcnt lgkmcnt(0)" ::: "memory");
    s8v bS[8];
#pragma unroll
    for (int ks = 0; ks < 8; ++ks)
      bS[ks] = *(const s8v*)&St[ln15 * 264 + ks * 32 + qw * 8];

    /* (2) dw = w @ S */
    f4v dwa0 = (f4v){0.f,0.f,0.f,0.f}, dwb0 = (f4v){0.f,0.f,0.f,0.f};
    f4v dwa1 = (f4v){0.f,0.f,0.f,0.f}, dwb1 = (f4v){0.f,0.f,0.f,0.f};
#pragma unroll
    for (int ks = 0; ks < 4; ++ks) {
      dwa0 = __builtin_amdgcn_mfma_f32_16x16x32_bf16(wA[0][ks], bS[ks], dwa0, 0, 0, 0);
      dwa1 = __builtin_amdgcn_mfma_f32_16x16x32_bf16(wA[1][ks], bS[ks], dwa1, 0, 0, 0);
      dwb0 = __builtin_amdgcn_mfma_f32_16x16x32_bf16(wA[0][ks + 4], bS[ks + 4], dwb0, 0, 0, 0);
      dwb1 = __builtin_amdgcn_mfma_f32_16x16x32_bf16(wA[1][ks + 4], bS[ks + 4], dwb1, 0, 0, 0);
    }
    float u2a[4], u2b[4];
#pragma unroll
    for (int r = 0; r < 4; ++r) {
      u2a[r] = uf[0][r] - (dwa0[r] + dwb0[r]);
      u2b[r] = uf[1][r] - (dwa1[r] + dwb1[r]);
    }
    /* u2^T redistribute via ds_bpermute (replaces Ut LDS round-trip).
       target lane (g=qw) word w pulls pair from source group 2*(g&1)+(w>>1);
       A-words (rows 0..15) for g<2, B-words (rows 16..31) for g>=2. */
    s8v bu;
    {
      int A0 = (int)pk2(u2a[0], u2a[1]);
      int A1 = (int)pk2(u2a[2], u2a[3]);
      int B0 = (int)pk2(u2b[0], u2b[1]);
      int B1 = (int)pk2(u2b[2], u2b[3]);
      int p0a = __builtin_amdgcn_ds_bpermute(idx0, A0);
      int p0b = __builtin_amdgcn_ds_bpermute(idx0, B0);
      int p1a = __builtin_amdgcn_ds_bpermute(idx0, A1);
      int p1b = __builtin_amdgcn_ds_bpermute(idx0, B1);
      int p2a = __builtin_amdgcn_ds_bpermute(idx1, A0);
      int p2b = __builtin_amdgcn_ds_bpermute(idx1, B0);
      int p3a = __builtin_amdgcn_ds_bpermute(idx1, A1);
      int p3b = __builtin_amdgcn_ds_bpermute(idx1, B1);
      int4 buw = make_int4(hiHalf ? p0b : p0a, hiHalf ? p1b : p1a,
                           hiHalf ? p2b : p2a, hiHalf ? p3b : p3a);
      bu = *(s8v*)&buw;
    }

    /* (3) attn part of o */
    f4v oA0 = __builtin_amdgcn_mfma_f32_16x16x32_bf16(atv[0], bu, (f4v){0.f,0.f,0.f,0.f}, 0, 0, 0);
    f4v oA1 = __builtin_amdgcn_mfma_f32_16x16x32_bf16(atv[1], bu, (f4v){0.f,0.f,0.f,0.f}, 0, 0, 0);

    /* (4) recurrence: S += kT @ u2 */
#pragma unroll
    for (int kt = 0; kt < 16; ++kt)
      Sacc[kt] = __builtin_amdgcn_mfma_f32_16x16x32_bf16(kA[kt], bu, Sacc[kt], 0, 0, 0);

    /* (5) prefetch chunk c+1 operands */
    if (c + 1 < NCHUNK) {
      const int ln = l0 + 32;
#pragma unroll
      for (int mt = 0; mt < 2; ++mt)
#pragma unroll
        for (int ks = 0; ks < 8; ++ks)
          wA[mt][ks] = *(const s8v*)(wbase + (long)(ln + mt * 16 + ln15) * 256 + ks * 32 + qw * 8);
#pragma unroll
      for (int kt = 0; kt < 16; ++kt)
        kA[kt] = *(const s8v*)(kTbase + (long)(c + 1) * 8192 + (kt * 16 + ln15) * 32 + qw * 8);
#pragma unroll
      for (int mt = 0; mt < 2; ++mt) {
        atv[mt] = *(const s8v*)(atbase + (long)(c + 1) * 1024 + (mt * 16 + ln15) * 32 + qw * 8);
#pragma unroll
        for (int r = 0; r < 4; ++r)
          uf[mt][r] = ubase[(long)(ln + mt * 16 + qw * 4 + r) * 256 + d0 + ln15];
      }
    }

    /* (6) o += q @ S (pre-update S, from bS regs) */
    f4v oB0 = (f4v){0.f,0.f,0.f,0.f}, oB1 = (f4v){0.f,0.f,0.f,0.f};
#pragma unroll
    for (int ks = 0; ks < 4; ++ks) {
      oA0 = __builtin_amdgcn_mfma_f32_16x16x32_bf16(qA[0][ks], bS[ks], oA0, 0, 0, 0);
      oA1 = __builtin_amdgcn_mfma_f32_16x16x32_bf16(qA[1][ks], bS[ks], oA1, 0, 0, 0);
      oB0 = __builtin_amdgcn_mfma_f32_16x16x32_bf16(qA[0][ks + 4], bS[ks + 4], oB0, 0, 0, 0);
      oB1 = __builtin_amdgcn_mfma_f32_16x16x32_bf16(qA[1][ks + 4], bS[ks + 4], oB1, 0, 0, 0);
    }
#pragma unroll
    for (int r = 0; r < 4; ++r) {
      dbase[(long)(l0 + qw * 4 + r) * 256 + d0 + ln15] = oA0[r] + oB0[r];
      dbase[(long)(l0 + 16 + qw * 4 + r) * 256 + d0 + ln15] = oA1[r] + oB1[r];
    }
  }
}

/* ================= fused kernels ================= */

__global__ __launch_bounds__(256) void head_fused(
    const float* __restrict__ x, __hip_bfloat16* __restrict__ xb,
    const float* __restrict__ Wb, const float* __restrict__ Wid,
    const float* __restrict__ alpha_id, const float* __restrict__ bidp,
    float* __restrict__ beta, float* __restrict__ idsc,
    const float* __restrict__ Wq, __hip_bfloat16* __restrict__ Wqt,
    const float* __restrict__ Wk, __hip_bfloat16* __restrict__ Wkt,
    const float* __restrict__ Wv, __hip_bfloat16* __restrict__ Wvt,
    const float* __restrict__ fir_s, const float* __restrict__ fir_l,
    float* __restrict__ fsT, float* __restrict__ flT) {
  __shared__ float tile[32][33];
  __shared__ float red[4][8];
  const int bid = blockIdx.x;
  if (bid < 8192) {
    prep_body(x, xb, Wb, Wid, alpha_id, bidp, beta, idsc, bid, red);
  } else if (bid < 9216) {
    int r = bid - 8192;
    tcast_body(Wq, Wqt, 1024, 1024, 1024, r & 31, r >> 5, tile);
  } else if (bid < 10240) {
    int r = bid - 9216;
    tcast_body(Wk, Wkt, 1024, 1024, 1024, r & 31, r >> 5, tile);
  } else if (bid < 11264) {
    int r = bid - 10240;
    tcast_body(Wv, Wvt, 1024, 1024, 1024, r & 31, r >> 5, tile);
  } else {
    firT_body(fir_s, fir_l, fsT, flT, bid - 11264);
  }
}

__global__ __launch_bounds__(256, 1) void phaseB_fir(
    const __hip_bfloat16* __restrict__ qpk, const __hip_bfloat16* __restrict__ wb,
    const __hip_bfloat16* __restrict__ kTb, const __hip_bfloat16* __restrict__ attnb,
    const float* __restrict__ u, float* __restrict__ delta,
    const float* __restrict__ v, const float* __restrict__ fsT,
    const float* __restrict__ flT, float* __restrict__ fs, float* __restrict__ fl) {
  __shared__ __align__(16) short Stb[4][16 * 264];
  const int bid = blockIdx.x;
  if (bid < 32) {
    __builtin_amdgcn_s_setprio(1);
    const int t = threadIdx.x;
    const int wv = t >> 6;
    const int lane = t & 63;
    const int unit = bid * 4 + wv;
    const int bh = unit >> 4;
    const int slice = unit & 15;
    phaseB_wave(qpk, wb, kTb, attnb, u, delta, bh, slice * 16, Stb[wv], lane);
  } else {
    fir_body(v, fsT, flT, fs, fl, bid - 32);
  }
}

__global__ __launch_bounds__(256) void stats_tcast(
    const float* __restrict__ x, const float* __restrict__ fs,
    const float* __restrict__ fl, const float* __restrict__ dl,
    __hip_bfloat16* __restrict__ rinb,
    const float* __restrict__ Wr1, __hip_bfloat16* __restrict__ Wr1t,
    const float* __restrict__ Wo, __hip_bfloat16* __restrict__ Wot) {
  __shared__ float tile[32][33];
  const int bid = blockIdx.x;
  if (bid < 8192) {
    stats_body(x, fs, fl, dl, rinb, bid);
  } else if (bid < 10304) {
    int r = bid - 8192;
    tcast_body(Wr1, Wr1t, 1048, 2048, 1056, r & 63, r >> 6, tile);
  } else {
    int r = bid - 10304;
    tcast_body(Wo, Wot, 1024, 1024, 1024, r & 31, r >> 5, tile);
  }
}

/* ---------------- bf16 MFMA GEMM: C = A(MxKs) * Bt(NxKs)^T ---------------- */
template <int ACT, bool BF16OUT>
__global__ __launch_bounds__(256) void gemm_bf16(
    const __hip_bfloat16* __restrict__ A, const __hip_bfloat16* __restrict__ Bt,
    const float* __restrict__ bias, void* __restrict__ Cv,
    int M, int N, int Ks) {
  __shared__ short As[128 * 32];
  __shared__ short Bs[128 * 32];
  const int t = threadIdx.x;
  const int wv = t >> 6;
  const int lane = t & 63;
  const int row0 = blockIdx.y * 128, col0 = blockIdx.x * 128;
  const int mq = (wv >> 1) * 64, nq = (wv & 1) * 64;
  const int ln15 = lane & 15;
  const int kq = (lane >> 4) * 8;
  const int sr = t >> 2;
  const int sc = (t & 3) * 8;
  const short* Ag = (const short*)A + (long)(row0 + sr) * Ks + sc;
  const short* Bg = (const short*)Bt + (long)(col0 + sr) * Ks + sc;
  const long rstep = (long)64 * Ks;

  f4v acc[4][4];
#pragma unroll
  for (int i = 0; i < 4; ++i)
#pragma unroll
    for (int j = 0; j < 4; ++j) acc[i][j] = (f4v){0.f, 0.f, 0.f, 0.f};

  uint4 a0 = *(const uint4*)(Ag);
  uint4 a1 = *(const uint4*)(Ag + rstep);
  uint4 b0 = *(const uint4*)(Bg);
  uint4 b1 = *(const uint4*)(Bg + rstep);
  for (int k0 = 0; k0 < Ks; k0 += 32) {
    __syncthreads();
    *(uint4*)&As[sr * 32 + sc] = a0;
    *(uint4*)&As[(sr + 64) * 32 + sc] = a1;
    *(uint4*)&Bs[sr * 32 + sc] = b0;
    *(uint4*)&Bs[(sr + 64) * 32 + sc] = b1;
    __syncthreads();
    if (k0 + 32 < Ks) {
      a0 = *(const uint4*)(Ag + k0 + 32);
      a1 = *(const uint4*)(Ag + rstep + k0 + 32);
      b0 = *(const uint4*)(Bg + k0 + 32);
      b1 = *(const uint4*)(Bg + rstep + k0 + 32);
    }
    s8v af[4], bf[4];
#pragma unroll
    for (int mt = 0; mt < 4; ++mt)
      af[mt] = *(const s8v*)&As[(mq + mt * 16 + ln15) * 32 + kq];
#pragma unroll
    for (int nt = 0; nt < 4; ++nt)
      bf[nt] = *(const s8v*)&Bs[(nq + nt * 16 + ln15) * 32 + kq];
#pragma unroll
    for (int mt = 0; mt < 4; ++mt)
#pragma unroll
      for (int nt = 0; nt < 4; ++nt)
        acc[mt][nt] = __builtin_amdgcn_mfma_f32_16x16x32_bf16(af[mt], bf[nt], acc[mt][nt], 0, 0, 0);
  }
  const int rbase = (lane >> 4) * 4;
#pragma unroll
  for (int mt = 0; mt < 4; ++mt) {
#pragma unroll
    for (int nt = 0; nt < 4; ++nt) {
      int gcol = col0 + nq + nt * 16 + ln15;
#pragma unroll
      for (int r = 0; r < 4; ++r) {
        int grow = row0 + mq + mt * 16 + rbase + r;
        float v = acc[mt][nt][r];
        if (ACT == 1) {
          v += bias[gcol];
          v = 0.5f * v * (1.0f + erff(v * 0.70710678118654752f));
        }
        if (BF16OUT) {
          ((__hip_bfloat16*)Cv)[(long)grow * N + gcol] = __float2bfloat16(v);
        } else {
          ((float*)Cv)[(long)grow * N + gcol] = v;
        }
      }
    }
  }
}

/* ---------- causal depthwise conv (K=4) + silu; MODE1 adds per-head l2norm ---------- */
template <int MODE>
__global__ __launch_bounds__(256) void conv_silu(
    const float* __restrict__ pre, const float* __restrict__ cw, float* __restrict__ out) {
  const int row = blockIdx.x;
  const int l = row & (SEQ - 1);
  const int t = threadIdx.x;
  const int cb = t * 4;
  float wts[4][4];
#pragma unroll
  for (int cc = 0; cc < 4; ++cc) {
    float4 w4 = *(const float4*)(cw + (cb + cc) * 4);
    wts[cc][0] = w4.x; wts[cc][1] = w4.y; wts[cc][2] = w4.z; wts[cc][3] = w4.w;
  }
  float acc[4] = {0, 0, 0, 0};
#pragma unroll
  for (int tap = 0; tap < 4; ++tap) {
    int lr = l - 3 + tap;
    if (lr >= 0) {
      float4 xv = *(const float4*)(pre + (long)(row - 3 + tap) * DMODEL + cb);
      acc[0] = fmaf(wts[0][tap], xv.x, acc[0]);
      acc[1] = fmaf(wts[1][tap], xv.y, acc[1]);
      acc[2] = fmaf(wts[2][tap], xv.z, acc[2]);
      acc[3] = fmaf(wts[3][tap], xv.w, acc[3]);
    }
  }
#pragma unroll
  for (int i = 0; i < 4; ++i) acc[i] = siluf(acc[i]);
  if (MODE == 1) {
    float ss = acc[0] * acc[0] + acc[1] * acc[1] + acc[2] * acc[2] + acc[3] * acc[3];
#pragma unroll
    for (int m = 1; m < 64; m <<= 1) ss += __shfl_xor(ss, m);
    float rn = rsqrtf(ss + 1e-6f);
#pragma unroll
    for (int i = 0; i < 4; ++i) acc[i] *= rn;
  }
  float4 ov = make_float4(acc[0], acc[1], acc[2], acc[3]);
  *(float4*)(out + (long)row * DMODEL + cb) = ov;
}

/* ---------- phase A v2: MFMA split-bf16 Gram products. ---------- */
__global__ __launch_bounds__(256) void phaseA(
    const float* __restrict__ qn, const float* __restrict__ kn, const float* __restrict__ v,
    const float* __restrict__ beta, float* __restrict__ u,
    __hip_bfloat16* __restrict__ wb16, __hip_bfloat16* __restrict__ kTb16,
    __hip_bfloat16* __restrict__ attnb16, __hip_bfloat16* __restrict__ qpk) {
  __shared__ short khi[32 * 264];
  __shared__ short klo[32 * 264];
  __shared__ float T[32][33];
  __shared__ float bet[32];
  const int bid = blockIdx.x;
  const int c = bid & (NCHUNK - 1);
  const int h = (bid >> 7) & 3;
  const int b = bid >> 9;
  const int bh = b * NH + h;
  const int l0 = c * 32;
  const int t = threadIdx.x;
  const int wv = t >> 6;
  const int lane = t & 63;
  const int ln15 = lane & 15;
  const int qw = lane >> 4;

#pragma unroll
  for (int r = 0; r < 8; ++r) {
    int idx = t + 256 * r;
    int i = idx >> 6;
    int f = (idx & 63) * 4;
    float4 kv = *(const float4*)(kn + ((long)(b * SEQ + l0 + i)) * DMODEL + h * DHEAD + f);
    float a[4] = {kv.x, kv.y, kv.z, kv.w};
    ushort4 hi4, lo4;
    unsigned short* hp = (unsigned short*)&hi4;
    unsigned short* lp = (unsigned short*)&lo4;
#pragma unroll
    for (int j = 0; j < 4; ++j) {
      unsigned short hb = f2b(a[j]);
      hp[j] = hb;
      lp[j] = f2b(a[j] - b2f(hb));
    }
    *(ushort4*)&khi[i * 264 + f] = hi4;
    *(ushort4*)&klo[i * 264 + f] = lo4;
  }
  if (t < 32) bet[t] = beta[(long)(b * SEQ + l0 + t) * NH + h];
  __syncthreads();

  if (wv < 2) {
    const int mt = wv;
    f4v acc0 = (f4v){0.f, 0.f, 0.f, 0.f};
    f4v acc1 = (f4v){0.f, 0.f, 0.f, 0.f};
#pragma unroll
    for (int ks = 0; ks < 8; ++ks) {
      s8v ahi = *(const s8v*)&khi[(mt * 16 + ln15) * 264 + ks * 32 + qw * 8];
      s8v alo = *(const s8v*)&klo[(mt * 16 + ln15) * 264 + ks * 32 + qw * 8];
      s8v bhi0 = *(const s8v*)&khi[ln15 * 264 + ks * 32 + qw * 8];
      s8v blo0 = *(const s8v*)&klo[ln15 * 264 + ks * 32 + qw * 8];
      s8v bhi1 = *(const s8v*)&khi[(16 + ln15) * 264 + ks * 32 + qw * 8];
      s8v blo1 = *(const s8v*)&klo[(16 + ln15) * 264 + ks * 32 + qw * 8];
      acc0 = __builtin_amdgcn_mfma_f32_16x16x32_bf16(ahi, bhi0, acc0, 0, 0, 0);
      acc0 = __builtin_amdgcn_mfma_f32_16x16x32_bf16(ahi, blo0, acc0, 0, 0, 0);
      acc0 = __builtin_amdgcn_mfma_f32_16x16x32_bf16(alo, bhi0, acc0, 0, 0, 0);
      acc1 = __builtin_amdgcn_mfma_f32_16x16x32_bf16(ahi, bhi1, acc1, 0, 0, 0);
      acc1 = __builtin_amdgcn_mfma_f32_16x16x32_bf16(ahi, blo1, acc1, 0, 0, 0);
      acc1 = __builtin_amdgcn_mfma_f32_16x16x32_bf16(alo, bhi1, acc1, 0, 0, 0);
    }
#pragma unroll
    for (int r = 0; r < 4; ++r) {
      int i = mt * 16 + qw * 4 + r;
      int j0 = ln15, j1 = 16 + ln15;
      T[i][j0] = (j0 < i) ? -bet[i] * acc0[r] : 0.f;
      T[i][j1] = (j1 < i) ? -bet[i] * acc1[r] : 0.f;
    }
  } else {
    const int mt = wv - 2;
    const long qoff = (long)(b * SEQ + l0 + mt * 16 + ln15) * DMODEL + h * DHEAD;
    __hip_bfloat16* qdst = qpk + ((long)bh * SEQ + l0 + mt * 16 + ln15) * DHEAD;
    f4v acc0 = (f4v){0.f, 0.f, 0.f, 0.f};
    f4v acc1 = (f4v){0.f, 0.f, 0.f, 0.f};
#pragma unroll
    for (int ks = 0; ks < 8; ++ks) {
      float4 q0 = *(const float4*)(qn + qoff + ks * 32 + qw * 8);
      float4 q1 = *(const float4*)(qn + qoff + ks * 32 + qw * 8 + 4);
      float a8[8] = {q0.x, q0.y, q0.z, q0.w, q1.x, q1.y, q1.z, q1.w};
      s8v ahi, alo;
#pragma unroll
      for (int j = 0; j < 8; ++j) {
        unsigned short hb = f2b(a8[j]);
        ahi[j] = (short)hb;
        alo[j] = (short)f2b(a8[j] - b2f(hb));
      }
      *(s8v*)(qdst + ks * 32 + qw * 8) = ahi;
      s8v bhi0 = *(const s8v*)&khi[ln15 * 264 + ks * 32 + qw * 8];
      s8v blo0 = *(const s8v*)&klo[ln15 * 264 + ks * 32 + qw * 8];
      s8v bhi1 = *(const s8v*)&khi[(16 + ln15) * 264 + ks * 32 + qw * 8];
      s8v blo1 = *(const s8v*)&klo[(16 + ln15) * 264 + ks * 32 + qw * 8];
      acc0 = __builtin_amdgcn_mfma_f32_16x16x32_bf16(ahi, bhi0, acc0, 0, 0, 0);
      acc0 = __builtin_amdgcn_mfma_f32_16x16x32_bf16(ahi, blo0, acc0, 0, 0, 0);
      acc0 = __builtin_amdgcn_mfma_f32_16x16x32_bf16(alo, bhi0, acc0, 0, 0, 0);
      acc1 = __builtin_amdgcn_mfma_f32_16x16x32_bf16(ahi, bhi1, acc1, 0, 0, 0);
      acc1 = __builtin_amdgcn_mfma_f32_16x16x32_bf16(ahi, blo1, acc1, 0, 0, 0);
      acc1 = __builtin_amdgcn_mfma_f32_16x16x32_bf16(alo, bhi1, acc1, 0, 0, 0);
    }
    long abase = ((long)bh * NCHUNK + c) * 1024;
#pragma unroll
    for (int r = 0; r < 4; ++r) {
      int i = mt * 16 + qw * 4 + r;
      int j0 = ln15, j1 = 16 + ln15;
      attnb16[abase + i * 32 + j0] = __float2bfloat16(j0 <= i ? acc0[r] : 0.f);
      attnb16[abase + i * 32 + j1] = __float2bfloat16(j1 <= i ? acc1[r] : 0.f);
    }
  }
  __syncthreads();

  if (t < 32) {
    const int l = t;
    for (int i = 1; i < 32; ++i) {
      float s = 0.f;
      for (int j = 0; j < i; ++j) s = fmaf(T[i][j], T[j][l], s);
      T[i][l] += s;
    }
    for (int i = 0; i < 32; ++i) {
      float val = T[i][l] + (i == l ? 1.f : 0.f);
      T[i][l] = val * bet[l];
    }
  }
  __syncthreads();

  {
    const int d = t;
    float acc[32];
#pragma unroll
    for (int i = 0; i < 32; ++i) acc[i] = 0.f;
    for (int j = 0; j < 32; ++j) {
      float vv = v[((long)(b * SEQ + l0 + j)) * DMODEL + h * DHEAD + d];
#pragma unroll
      for (int i = 0; i < 32; ++i) acc[i] = fmaf(T[i][j], vv, acc[i]);
    }
    long ubase = ((long)bh * SEQ + l0) * DHEAD + d;
#pragma unroll
    for (int i = 0; i < 32; ++i) u[ubase + (long)i * DHEAD] = acc[i];
#pragma unroll
    for (int i = 0; i < 32; ++i) acc[i] = 0.f;
    for (int j = 0; j < 32; ++j) {
      float kv = b2f((unsigned short)khi[j * 264 + d]) + b2f((unsigned short)klo[j * 264 + d]);
#pragma unroll
      for (int i = 0; i < 32; ++i) acc[i] = fmaf(T[i][j], kv, acc[i]);
    }
#pragma unroll
    for (int i = 0; i < 32; ++i) wb16[ubase + (long)i * DHEAD] = __float2bfloat16(acc[i]);
  }

  {
    const int s = t;
    unsigned short* kb = (unsigned short*)kTb16 + ((long)bh * NCHUNK + c) * 8192 + (long)s * 32;
#pragma unroll
    for (int i4 = 0; i4 < 8; ++i4) {
      ushort4 pk;
      pk.x = (unsigned short)khi[(i4 * 4 + 0) * 264 + s];
      pk.y = (unsigned short)khi[(i4 * 4 + 1) * 264 + s];
      pk.z = (unsigned short)khi[(i4 * 4 + 2) * 264 + s];
      pk.w = (unsigned short)khi[(i4 * 4 + 3) * 264 + s];
      *(ushort4*)(kb + i4 * 4) = pk;
    }
  }
}

/* ---------- logits from bf16 hmid ; p = softmax(logits/tau)*0.925+0.025 ---------- */
__global__ __launch_bounds__(256) void router_logits(
    const __hip_bfloat16* __restrict__ hmid, const float* __restrict__ Wr2,
    const float* __restrict__ br2, const float* __restrict__ ltg, float* __restrict__ p) {
  const int row = blockIdx.x;
  const int t = threadIdx.x;
  float acc[12];
#pragma unroll
  for (int j = 0; j < 12; ++j) acc[j] = 0.f;
  const __hip_bfloat16* hr = hmid + (long)row * 2048;
  for (int k = t; k < 2048; k += 256) {
    float hv = __bfloat162float(hr[k]);
    const float* wr = Wr2 + k * 12;
#pragma unroll
    for (int j = 0; j < 12; ++j) acc[j] = fmaf(hv, wr[j], acc[j]);
  }
#pragma unroll
  for (int m = 1; m < 64; m <<= 1)
#pragma unroll
    for (int j = 0; j < 12; ++j) acc[j] += __shfl_xor(acc[j], m);
  __shared__ float red[4][12];
  if ((t & 63) == 0) {
    int wv = t >> 6;
#pragma unroll
    for (int j = 0; j < 12; ++j) red[wv][j] = acc[j];
  }
  __syncthreads();
  if (t < 4) {
    const int h = t;
    float l3[3];
#pragma unroll
    for (int j = 0; j < 3; ++j) {
      int col = h * 3 + j;
      l3[j] = red[0][col] + red[1][col] + red[2][col] + red[3][col] + br2[col];
    }
    float inv_tau = expf(-ltg[h >> 1]);
    float y0 = l3[0] * inv_tau, y1 = l3[1] * inv_tau, y2 = l3[2] * inv_tau;
    float mx = fmaxf(y0, fmaxf(y1, y2));
    float e0 = expf(y0 - mx), e1 = expf(y1 - mx), e2 = expf(y2 - mx);
    float inv = 1.f / (e0 + e1 + e2);
    p[(long)row * 12 + h * 3 + 0] = e0 * inv * 0.925f + 0.025f;
    p[(long)row * 12 + h * 3 + 1] = e1 * inv * 0.925f + 0.025f;
    p[(long)row * 12 + h * 3 + 2] = e2 * inv * 0.925f + 0.025f;
  }
}

/* ---------- mixture + identity + RMS norm -> bf16 out. delta layout (B,H,L,DV). ---------- */
__global__ __launch_bounds__(256) void omix(
    const float* __restrict__ fs, const float* __restrict__ fl,
    const float* __restrict__ dl, const float* __restrict__ vh,
    const float* __restrict__ p, const float* __restrict__ idsc,
    const float* __restrict__ onw, __hip_bfloat16* __restrict__ o) {
  const int row = blockIdx.x;
  const int b = row >> 12;
  const int l = row & (SEQ - 1);
  const int t = threadIdx.x;
  const int h = t >> 6;
  const int lane = t & 63;
  const long base = (long)row * DMODEL + h * DHEAD + lane * 4;
  const long dbase = ((long)(b * NH + h) * SEQ + l) * DHEAD + lane * 4;
  float p0 = p[(long)row * 12 + h * 3 + 0];
  float p1 = p[(long)row * 12 + h * 3 + 1];
  float p2 = p[(long)row * 12 + h * 3 + 2];
  float idv = idsc[(long)row * NH + h];
  float4 a = *(const float4*)(fs + base);
  float4 bq = *(const float4*)(fl + base);
  float4 cq = *(const float4*)(dl + dbase);
  float4 vv = *(const float4*)(vh + base);
  float4 ov;
  ov.x = p0 * a.x + p1 * bq.x + p2 * cq.x + idv * vv.x;
  ov.y = p0 * a.y + p1 * bq.y + p2 * cq.y + idv * vv.y;
  ov.z = p0 * a.z + p1 * bq.z + p2 * cq.z + idv * vv.z;
  ov.w = p0 * a.w + p1 * bq.w + p2 * cq.w + idv * vv.w;
  float ss = ov.x * ov.x + ov.y * ov.y + ov.z * ov.z + ov.w * ov.w;
#pragma unroll
  for (int m = 1; m < 64; m <<= 1) ss += __shfl_xor(ss, m);
  float rms = rsqrtf(ss * (1.f / 256.f) + 1e-5f);
  float4 wn = *(const float4*)(onw + lane * 4);
  __hip_bfloat16 tmp[4] = {__float2bfloat16(ov.x * rms * wn.x),
                           __float2bfloat16(ov.y * rms * wn.y),
                           __float2bfloat16(ov.z * rms * wn.z),
                           __float2bfloat16(ov.w * rms * wn.w)};
  *(ushort4*)(o + base) = *(ushort4*)tmp;
}

extern "C" void kernel_launch(void* const* d_in, const int* in_sizes, int n_in,
                              void* d_out, int out_size, void* d_ws, size_t ws_size,
                              hipStream_t stream) {
  const float* x = (const float*)d_in[0];
  const float* Wq = (const float*)d_in[1];
  const float* Wk = (const float*)d_in[2];
  const float* Wv = (const float*)d_in[3];
  const float* Wb = (const float*)d_in[4];
  const float* conv_q = (const float*)d_in[5];
  const float* conv_k = (const float*)d_in[6];
  const float* conv_v = (const float*)d_in[7];
  const float* fir_s = (const float*)d_in[8];
  const float* fir_l = (const float*)d_in[9];
  const float* alpha_id = (const float*)d_in[10];
  const float* Wid = (const float*)d_in[11];
  const float* bidp = (const float*)d_in[12];
  const float* Wr1 = (const float*)d_in[13];
  const float* br1 = (const float*)d_in[14];
  const float* Wr2 = (const float*)d_in[15];
  const float* br2 = (const float*)d_in[16];
  const float* ltg = (const float*)d_in[17];
  const float* onw = (const float*)d_in[19];
  const float* Wo = (const float*)d_in[20];

  float* ws = (float*)d_ws;
  float* pre = ws + 0;
  float* ubuf = ws + 8388608;
  float* wbuf = ws + 16777216;
  float* attnbuf = ws + 25165824;
  float* qbuf = ws + 26214400;
  float* kbuf = ws + 34603008;
  float* vbuf = ws + 42991616;
  float* betabuf = ws + 51380224;
  float* idscbuf = ws + 51412992;
  float* pbuf = ws + 51445760;
  float* flTb = ws + 51544064;  /* 31*1024 */
  float* fsTb = ws + 51575808;  /* 3*1024, end 51578880 (~206.3 MB) */
  float* deltabuf = ubuf;
  __hip_bfloat16* xb = (__hip_bfloat16*)ubuf;
  __hip_bfloat16* Wqt = (__hip_bfloat16*)(wbuf);
  __hip_bfloat16* Wkt = (__hip_bfloat16*)(wbuf + 524288);
  __hip_bfloat16* Wvt = (__hip_bfloat16*)(wbuf + 1048576);
  __hip_bfloat16* wb16 = (__hip_bfloat16*)wbuf;
  __hip_bfloat16* kTb16 = (__hip_bfloat16*)wbuf + 8388608;
  __hip_bfloat16* attnb16 = (__hip_bfloat16*)attnbuf;
  __hip_bfloat16* qpk16 = (__hip_bfloat16*)pre;
  __hip_bfloat16* rinb = (__hip_bfloat16*)(wbuf);
  __hip_bfloat16* Wr1t = (__hip_bfloat16*)(wbuf + 4325376);
  __hip_bfloat16* Wot = (__hip_bfloat16*)(wbuf + 5406720);
  __hip_bfloat16* omixb = (__hip_bfloat16*)(wbuf);
  __hip_bfloat16* hmid = (__hip_bfloat16*)pre;
  float* fsb = qbuf;
  float* flb = kbuf;

  dim3 blk(256);
  head_fused<<<dim3(11298), blk, 0, stream>>>(x, xb, Wb, Wid, alpha_id, bidp,
      betabuf, idscbuf, Wq, Wqt, Wk, Wkt, Wv, Wvt, fir_s, fir_l, fsTb, flTb);
  gemm_bf16<0, false><<<dim3(8, 64), blk, 0, stream>>>(xb, Wqt, nullptr, pre, ROWS, 1024, 1024);
  conv_silu<1><<<dim3(ROWS), blk, 0, stream>>>(pre, conv_q, qbuf);
  gemm_bf16<0, false><<<dim3(8, 64), blk, 0, stream>>>(xb, Wkt, nullptr, pre, ROWS, 1024, 1024);
  conv_silu<1><<<dim3(ROWS), blk, 0, stream>>>(pre, conv_k, kbuf);
  gemm_bf16<0, false><<<dim3(8, 64), blk, 0, stream>>>(xb, Wvt, nullptr, pre, ROWS, 1024, 1024);
  conv_silu<0><<<dim3(ROWS), blk, 0, stream>>>(pre, conv_v, vbuf);
  phaseA<<<dim3(BATCH * NH * NCHUNK), blk, 0, stream>>>(qbuf, kbuf, vbuf, betabuf, ubuf, wb16, kTb16, attnb16, qpk16);
  phaseB_fir<<<dim3(32 + ROWS), blk, 0, stream>>>(qpk16, wb16, kTb16, attnb16, ubuf, deltabuf,
      vbuf, fsTb, flTb, fsb, flb);
  stats_tcast<<<dim3(11328), blk, 0, stream>>>(x, fsb, flb, deltabuf, rinb, Wr1, Wr1t, Wo, Wot);
  gemm_bf16<1, true><<<dim3(16, 64), blk, 0, stream>>>(rinb, Wr1t, br1, hmid, ROWS, 2048, 1056);
  router_logits<<<dim3(ROWS), blk, 0, stream>>>(hmid, Wr2, br2, ltg, pbuf);
  omix<<<dim3(ROWS), blk, 0, stream>>>(fsb, flb, deltabuf, vbuf, pbuf, idscbuf, onw, omixb);
  gemm_bf16<0, false><<<dim3(8, 64), blk, 0, stream>>>(omixb, Wot, nullptr, d_out, ROWS, 1024, 1024);
}

// Round 4
// 903.794 us; speedup vs baseline: 1.2986x; 1.2986x over previous
//
#include <hip/hip_runtime.h>
#include <hip/hip_bf16.h>
#include <math.h>

#define BATCH 2
#define SEQ 4096
#define DMODEL 1024
#define NH 4
#define DHEAD 256
#define NCHUNK 128
#define ROWS (BATCH * SEQ) /* 8192 */

typedef short s8v __attribute__((ext_vector_type(8)));   /* 8 bf16 in 4 VGPRs */
typedef float f4v __attribute__((ext_vector_type(4)));

__device__ __forceinline__ float sigm(float x) { return 1.0f / (1.0f + expf(-x)); }
__device__ __forceinline__ float siluf(float x) { return x / (1.0f + expf(-x)); }
__device__ __forceinline__ unsigned short f2b(float f) {
  __hip_bfloat16 h = __float2bfloat16(f);
  return *(unsigned short*)&h;
}
__device__ __forceinline__ float b2f(unsigned short u) {
  __hip_bfloat16 h = *(__hip_bfloat16*)&u;
  return __bfloat162float(h);
}
__device__ __forceinline__ unsigned int pk2(float lo, float hi) {
  return (unsigned int)f2b(lo) | ((unsigned int)f2b(hi) << 16);
}
__device__ __forceinline__ void gload16(const short* g, short* l) {
  __builtin_amdgcn_global_load_lds(
      (const __attribute__((address_space(1))) unsigned int*)(const void*)g,
      (__attribute__((address_space(3))) unsigned int*)(void*)l, 16, 0, 0);
}

/* ================= device bodies for fused head/tail kernels ================= */

__device__ __forceinline__ void prep_body(
    const float* __restrict__ x, __hip_bfloat16* __restrict__ xb,
    const float* __restrict__ Wb, const float* __restrict__ Wid,
    const float* __restrict__ alpha_id, const float* __restrict__ bidp,
    float* __restrict__ beta, float* __restrict__ idsc, int row,
    float (*red)[8]) {
  const int t = threadIdx.x;
  const long base = (long)row * DMODEL + t * 4;
  float4 xv = *(const float4*)(x + base);
  {
    __hip_bfloat16 tmp[4] = {__float2bfloat16(xv.x), __float2bfloat16(xv.y),
                             __float2bfloat16(xv.z), __float2bfloat16(xv.w)};
    *(ushort4*)(xb + base) = *(ushort4*)tmp;
  }
  float xa[4] = {xv.x, xv.y, xv.z, xv.w};
  float ab[4] = {0, 0, 0, 0}, ai[4] = {0, 0, 0, 0};
#pragma unroll
  for (int i = 0; i < 4; ++i) {
    int k = t * 4 + i;
    float4 wb4 = *(const float4*)(Wb + k * 4);
    float4 wi4 = *(const float4*)(Wid + k * 4);
    ab[0] = fmaf(xa[i], wb4.x, ab[0]); ab[1] = fmaf(xa[i], wb4.y, ab[1]);
    ab[2] = fmaf(xa[i], wb4.z, ab[2]); ab[3] = fmaf(xa[i], wb4.w, ab[3]);
    ai[0] = fmaf(xa[i], wi4.x, ai[0]); ai[1] = fmaf(xa[i], wi4.y, ai[1]);
    ai[2] = fmaf(xa[i], wi4.z, ai[2]); ai[3] = fmaf(xa[i], wi4.w, ai[3]);
  }
#pragma unroll
  for (int m = 1; m < 64; m <<= 1) {
#pragma unroll
    for (int hh = 0; hh < 4; ++hh) {
      ab[hh] += __shfl_xor(ab[hh], m);
      ai[hh] += __shfl_xor(ai[hh], m);
    }
  }
  if ((t & 63) == 0) {
    int wv = t >> 6;
#pragma unroll
    for (int hh = 0; hh < 4; ++hh) {
      red[wv][hh] = ab[hh];
      red[wv][4 + hh] = ai[hh];
    }
  }
  __syncthreads();
  if (t < 8) {
    float s = red[0][t] + red[1][t] + red[2][t] + red[3][t];
    if (t < 4) {
      beta[(long)row * NH + t] = sigm(s);
    } else {
      int hh = t - 4;
      idsc[(long)row * NH + hh] = 0.06f + sigm(alpha_id[hh]) * sigm(s + bidp[hh]);
    }
  }
}

__device__ __forceinline__ void tcast_body(
    const float* __restrict__ W, __hip_bfloat16* __restrict__ Wt,
    int K, int N, int Ks, int bx, int by, float (*tile)[33]) {
  const int t = threadIdx.x;
  const int tx = t & 31, ty = t >> 5;
  const int kb = by * 32, nb = bx * 32;
#pragma unroll
  for (int r = 0; r < 4; ++r) {
    int kk = kb + ty + 8 * r;
    tile[ty + 8 * r][tx] = (kk < K) ? W[(long)kk * N + nb + tx] : 0.f;
  }
  __syncthreads();
#pragma unroll
  for (int r = 0; r < 4; ++r) {
    Wt[(long)(nb + ty + 8 * r) * Ks + kb + tx] = __float2bfloat16(tile[tx][ty + 8 * r]);
  }
}

__device__ __forceinline__ void firT_body(
    const float* __restrict__ fshort, const float* __restrict__ flong,
    float* __restrict__ fsT, float* __restrict__ flT, int j) {
  const int t = threadIdx.x;
  if (j < 31) {
#pragma unroll
    for (int i = 0; i < 4; ++i) {
      int c = t * 4 + i;
      flT[j * 1024 + c] = flong[c * 31 + j];
    }
  } else {
    int tp = j - 31;
#pragma unroll
    for (int i = 0; i < 4; ++i) {
      int c = t * 4 + i;
      fsT[tp * 1024 + c] = fshort[c * 3 + tp];
    }
  }
}

__device__ __forceinline__ void stats_body(
    const float* __restrict__ x, const float* __restrict__ fs,
    const float* __restrict__ fl, const float* __restrict__ dl,
    __hip_bfloat16* __restrict__ rinb, int row) {
  const int b = row >> 12;
  const int l = row & (SEQ - 1);
  const int t = threadIdx.x;
  float4 xv = *(const float4*)(x + (long)row * DMODEL + t * 4);
  {
    __hip_bfloat16 tmp[4] = {__float2bfloat16(xv.x), __float2bfloat16(xv.y),
                             __float2bfloat16(xv.z), __float2bfloat16(xv.w)};
    *(ushort4*)(rinb + (long)row * 1056 + t * 4) = *(ushort4*)tmp;
  }
  if (t < 8) rinb[(long)row * 1056 + 1048 + t] = __float2bfloat16(0.f);
  const int h = t >> 6;
  const int lane = t & 63;
  const long base = (long)row * DMODEL + h * DHEAD + lane * 4;
  const long dbase = ((long)(b * NH + h) * SEQ + l) * DHEAD + lane * 4;
  float4 a = *(const float4*)(fs + base);
  float4 bq = *(const float4*)(fl + base);
  float4 cq = *(const float4*)(dl + dbase);
  float s[6];
  s[0] = a.x + a.y + a.z + a.w;
  s[1] = a.x * a.x + a.y * a.y + a.z * a.z + a.w * a.w;
  s[2] = bq.x + bq.y + bq.z + bq.w;
  s[3] = bq.x * bq.x + bq.y * bq.y + bq.z * bq.z + bq.w * bq.w;
  s[4] = cq.x + cq.y + cq.z + cq.w;
  s[5] = cq.x * cq.x + cq.y * cq.y + cq.z * cq.z + cq.w * cq.w;
#pragma unroll
  for (int m = 1; m < 64; m <<= 1)
#pragma unroll
    for (int j = 0; j < 6; ++j) s[j] += __shfl_xor(s[j], m);
  if (lane == 0) {
    __hip_bfloat16* rb = rinb + (long)row * 1056 + 1024;
    float m0 = s[0] * (1.f / 256.f);
    float m1 = s[2] * (1.f / 256.f);
    float m2 = s[4] * (1.f / 256.f);
    rb[h] = __float2bfloat16(m0);
    rb[4 + h] = __float2bfloat16(sqrtf(fmaxf(s[1] * (1.f / 256.f) - m0 * m0, 0.f)));
    rb[8 + h] = __float2bfloat16(m1);
    rb[12 + h] = __float2bfloat16(sqrtf(fmaxf(s[3] * (1.f / 256.f) - m1 * m1, 0.f)));
    rb[16 + h] = __float2bfloat16(m2);
    rb[20 + h] = __float2bfloat16(sqrtf(fmaxf(s[5] * (1.f / 256.f) - m2 * m2, 0.f)));
  }
}

/* ================= fused head/tail kernels ================= */

__global__ __launch_bounds__(256) void head_fused(
    const float* __restrict__ x, __hip_bfloat16* __restrict__ xb,
    const float* __restrict__ Wb, const float* __restrict__ Wid,
    const float* __restrict__ alpha_id, const float* __restrict__ bidp,
    float* __restrict__ beta, float* __restrict__ idsc,
    const float* __restrict__ Wq, __hip_bfloat16* __restrict__ Wqt,
    const float* __restrict__ Wk, __hip_bfloat16* __restrict__ Wkt,
    const float* __restrict__ Wv, __hip_bfloat16* __restrict__ Wvt,
    const float* __restrict__ fir_s, const float* __restrict__ fir_l,
    float* __restrict__ fsT, float* __restrict__ flT) {
  __shared__ float tile[32][33];
  __shared__ float red[4][8];
  const int bid = blockIdx.x;
  if (bid < 8192) {
    prep_body(x, xb, Wb, Wid, alpha_id, bidp, beta, idsc, bid, red);
  } else if (bid < 9216) {
    int r = bid - 8192;
    tcast_body(Wq, Wqt, 1024, 1024, 1024, r & 31, r >> 5, tile);
  } else if (bid < 10240) {
    int r = bid - 9216;
    tcast_body(Wk, Wkt, 1024, 1024, 1024, r & 31, r >> 5, tile);
  } else if (bid < 11264) {
    int r = bid - 10240;
    tcast_body(Wv, Wvt, 1024, 1024, 1024, r & 31, r >> 5, tile);
  } else {
    firT_body(fir_s, fir_l, fsT, flT, bid - 11264);
  }
}

__global__ __launch_bounds__(256) void stats_tcast(
    const float* __restrict__ x, const float* __restrict__ fs,
    const float* __restrict__ fl, const float* __restrict__ dl,
    __hip_bfloat16* __restrict__ rinb,
    const float* __restrict__ Wr1, __hip_bfloat16* __restrict__ Wr1t,
    const float* __restrict__ Wo, __hip_bfloat16* __restrict__ Wot) {
  __shared__ float tile[32][33];
  const int bid = blockIdx.x;
  if (bid < 8192) {
    stats_body(x, fs, fl, dl, rinb, bid);
  } else if (bid < 10304) {
    int r = bid - 8192;
    tcast_body(Wr1, Wr1t, 1048, 2048, 1056, r & 63, r >> 6, tile);
  } else {
    int r = bid - 10304;
    tcast_body(Wo, Wot, 1024, 1024, 1024, r & 31, r >> 5, tile);
  }
}

/* ---------------- bf16 MFMA GEMM: C = A(MxKs) * Bt(NxKs)^T
   staging via global_load_lds width-16 (4 DMA / wave / K-step) ---------------- */
template <int ACT, bool BF16OUT>
__global__ __launch_bounds__(256) void gemm_bf16(
    const __hip_bfloat16* __restrict__ A, const __hip_bfloat16* __restrict__ Bt,
    const float* __restrict__ bias, void* __restrict__ Cv,
    int M, int N, int Ks) {
  __shared__ short As[128 * 32];
  __shared__ short Bs[128 * 32];
  const int t = threadIdx.x;
  const int wv = t >> 6;
  const int lane = t & 63;
  const int row0 = blockIdx.y * 128, col0 = blockIdx.x * 128;
  const int mq = (wv >> 1) * 64, nq = (wv & 1) * 64;
  const int ln15 = lane & 15;
  const int kq = (lane >> 4) * 8;
  /* staging: wave wv covers rows [wv*16, wv*16+16) and +64; lane -> row wv*16+(lane>>2), col (lane&3)*8 */
  const int srow = wv * 16 + (lane >> 2);
  const int scol = (lane & 3) * 8;
  const short* Ag0 = (const short*)A + (long)(row0 + srow) * Ks + scol;
  const short* Ag1 = Ag0 + (long)64 * Ks;
  const short* Bg0 = (const short*)Bt + (long)(col0 + srow) * Ks + scol;
  const short* Bg1 = Bg0 + (long)64 * Ks;
  short* Ad0 = &As[(wv * 16) * 32];
  short* Ad1 = &As[(64 + wv * 16) * 32];
  short* Bd0 = &Bs[(wv * 16) * 32];
  short* Bd1 = &Bs[(64 + wv * 16) * 32];

  f4v acc[4][4];
#pragma unroll
  for (int i = 0; i < 4; ++i)
#pragma unroll
    for (int j = 0; j < 4; ++j) acc[i][j] = (f4v){0.f, 0.f, 0.f, 0.f};

  for (int k0 = 0; k0 < Ks; k0 += 32) {
    __syncthreads();
    gload16(Ag0 + k0, Ad0);
    gload16(Ag1 + k0, Ad1);
    gload16(Bg0 + k0, Bd0);
    gload16(Bg1 + k0, Bd1);
    __syncthreads();
    s8v af[4], bf[4];
#pragma unroll
    for (int mt = 0; mt < 4; ++mt)
      af[mt] = *(const s8v*)&As[(mq + mt * 16 + ln15) * 32 + kq];
#pragma unroll
    for (int nt = 0; nt < 4; ++nt)
      bf[nt] = *(const s8v*)&Bs[(nq + nt * 16 + ln15) * 32 + kq];
#pragma unroll
    for (int mt = 0; mt < 4; ++mt)
#pragma unroll
      for (int nt = 0; nt < 4; ++nt)
        acc[mt][nt] = __builtin_amdgcn_mfma_f32_16x16x32_bf16(af[mt], bf[nt], acc[mt][nt], 0, 0, 0);
  }
  const int rbase = (lane >> 4) * 4;
#pragma unroll
  for (int mt = 0; mt < 4; ++mt) {
#pragma unroll
    for (int nt = 0; nt < 4; ++nt) {
      int gcol = col0 + nq + nt * 16 + ln15;
#pragma unroll
      for (int r = 0; r < 4; ++r) {
        int grow = row0 + mq + mt * 16 + rbase + r;
        float v = acc[mt][nt][r];
        if (ACT == 1) {
          v += bias[gcol];
          v = 0.5f * v * (1.0f + erff(v * 0.70710678118654752f));
        }
        if (BF16OUT) {
          ((__hip_bfloat16*)Cv)[(long)grow * N + gcol] = __float2bfloat16(v);
        } else {
          ((float*)Cv)[(long)grow * N + gcol] = v;
        }
      }
    }
  }
}

/* ---------- causal depthwise conv (K=4) + silu; MODE1 adds per-head l2norm ---------- */
template <int MODE>
__global__ __launch_bounds__(256) void conv_silu(
    const float* __restrict__ pre, const float* __restrict__ cw, float* __restrict__ out) {
  const int row = blockIdx.x;
  const int l = row & (SEQ - 1);
  const int t = threadIdx.x;
  const int cb = t * 4;
  float wts[4][4];
#pragma unroll
  for (int cc = 0; cc < 4; ++cc) {
    float4 w4 = *(const float4*)(cw + (cb + cc) * 4);
    wts[cc][0] = w4.x; wts[cc][1] = w4.y; wts[cc][2] = w4.z; wts[cc][3] = w4.w;
  }
  float acc[4] = {0, 0, 0, 0};
#pragma unroll
  for (int tap = 0; tap < 4; ++tap) {
    int lr = l - 3 + tap;
    if (lr >= 0) {
      float4 xv = *(const float4*)(pre + (long)(row - 3 + tap) * DMODEL + cb);
      acc[0] = fmaf(wts[0][tap], xv.x, acc[0]);
      acc[1] = fmaf(wts[1][tap], xv.y, acc[1]);
      acc[2] = fmaf(wts[2][tap], xv.z, acc[2]);
      acc[3] = fmaf(wts[3][tap], xv.w, acc[3]);
    }
  }
#pragma unroll
  for (int i = 0; i < 4; ++i) acc[i] = siluf(acc[i]);
  if (MODE == 1) {
    float ss = acc[0] * acc[0] + acc[1] * acc[1] + acc[2] * acc[2] + acc[3] * acc[3];
#pragma unroll
    for (int m = 1; m < 64; m <<= 1) ss += __shfl_xor(ss, m);
    float rn = rsqrtf(ss + 1e-6f);
#pragma unroll
    for (int i = 0; i < 4; ++i) acc[i] *= rn;
  }
  float4 ov = make_float4(acc[0], acc[1], acc[2], acc[3]);
  *(float4*)(out + (long)row * DMODEL + cb) = ov;
}

/* ---------- phase A v2: MFMA split-bf16 Gram products. ---------- */
__global__ __launch_bounds__(256) void phaseA(
    const float* __restrict__ qn, const float* __restrict__ kn, const float* __restrict__ v,
    const float* __restrict__ beta, float* __restrict__ u,
    __hip_bfloat16* __restrict__ wb16, __hip_bfloat16* __restrict__ kTb16,
    __hip_bfloat16* __restrict__ attnb16, __hip_bfloat16* __restrict__ qpk) {
  __shared__ short khi[32 * 264];
  __shared__ short klo[32 * 264];
  __shared__ float T[32][33];
  __shared__ float bet[32];
  const int bid = blockIdx.x;
  const int c = bid & (NCHUNK - 1);
  const int h = (bid >> 7) & 3;
  const int b = bid >> 9;
  const int bh = b * NH + h;
  const int l0 = c * 32;
  const int t = threadIdx.x;
  const int wv = t >> 6;
  const int lane = t & 63;
  const int ln15 = lane & 15;
  const int qw = lane >> 4;

#pragma unroll
  for (int r = 0; r < 8; ++r) {
    int idx = t + 256 * r;
    int i = idx >> 6;
    int f = (idx & 63) * 4;
    float4 kv = *(const float4*)(kn + ((long)(b * SEQ + l0 + i)) * DMODEL + h * DHEAD + f);
    float a[4] = {kv.x, kv.y, kv.z, kv.w};
    ushort4 hi4, lo4;
    unsigned short* hp = (unsigned short*)&hi4;
    unsigned short* lp = (unsigned short*)&lo4;
#pragma unroll
    for (int j = 0; j < 4; ++j) {
      unsigned short hb = f2b(a[j]);
      hp[j] = hb;
      lp[j] = f2b(a[j] - b2f(hb));
    }
    *(ushort4*)&khi[i * 264 + f] = hi4;
    *(ushort4*)&klo[i * 264 + f] = lo4;
  }
  if (t < 32) bet[t] = beta[(long)(b * SEQ + l0 + t) * NH + h];
  __syncthreads();

  if (wv < 2) {
    const int mt = wv;
    f4v acc0 = (f4v){0.f, 0.f, 0.f, 0.f};
    f4v acc1 = (f4v){0.f, 0.f, 0.f, 0.f};
#pragma unroll
    for (int ks = 0; ks < 8; ++ks) {
      s8v ahi = *(const s8v*)&khi[(mt * 16 + ln15) * 264 + ks * 32 + qw * 8];
      s8v alo = *(const s8v*)&klo[(mt * 16 + ln15) * 264 + ks * 32 + qw * 8];
      s8v bhi0 = *(const s8v*)&khi[ln15 * 264 + ks * 32 + qw * 8];
      s8v blo0 = *(const s8v*)&klo[ln15 * 264 + ks * 32 + qw * 8];
      s8v bhi1 = *(const s8v*)&khi[(16 + ln15) * 264 + ks * 32 + qw * 8];
      s8v blo1 = *(const s8v*)&klo[(16 + ln15) * 264 + ks * 32 + qw * 8];
      acc0 = __builtin_amdgcn_mfma_f32_16x16x32_bf16(ahi, bhi0, acc0, 0, 0, 0);
      acc0 = __builtin_amdgcn_mfma_f32_16x16x32_bf16(ahi, blo0, acc0, 0, 0, 0);
      acc0 = __builtin_amdgcn_mfma_f32_16x16x32_bf16(alo, bhi0, acc0, 0, 0, 0);
      acc1 = __builtin_amdgcn_mfma_f32_16x16x32_bf16(ahi, bhi1, acc1, 0, 0, 0);
      acc1 = __builtin_amdgcn_mfma_f32_16x16x32_bf16(ahi, blo1, acc1, 0, 0, 0);
      acc1 = __builtin_amdgcn_mfma_f32_16x16x32_bf16(alo, bhi1, acc1, 0, 0, 0);
    }
#pragma unroll
    for (int r = 0; r < 4; ++r) {
      int i = mt * 16 + qw * 4 + r;
      int j0 = ln15, j1 = 16 + ln15;
      T[i][j0] = (j0 < i) ? -bet[i] * acc0[r] : 0.f;
      T[i][j1] = (j1 < i) ? -bet[i] * acc1[r] : 0.f;
    }
  } else {
    const int mt = wv - 2;
    const long qoff = (long)(b * SEQ + l0 + mt * 16 + ln15) * DMODEL + h * DHEAD;
    __hip_bfloat16* qdst = qpk + ((long)bh * SEQ + l0 + mt * 16 + ln15) * DHEAD;
    f4v acc0 = (f4v){0.f, 0.f, 0.f, 0.f};
    f4v acc1 = (f4v){0.f, 0.f, 0.f, 0.f};
#pragma unroll
    for (int ks = 0; ks < 8; ++ks) {
      float4 q0 = *(const float4*)(qn + qoff + ks * 32 + qw * 8);
      float4 q1 = *(const float4*)(qn + qoff + ks * 32 + qw * 8 + 4);
      float a8[8] = {q0.x, q0.y, q0.z, q0.w, q1.x, q1.y, q1.z, q1.w};
      s8v ahi, alo;
#pragma unroll
      for (int j = 0; j < 8; ++j) {
        unsigned short hb = f2b(a8[j]);
        ahi[j] = (short)hb;
        alo[j] = (short)f2b(a8[j] - b2f(hb));
      }
      *(s8v*)(qdst + ks * 32 + qw * 8) = ahi;
      s8v bhi0 = *(const s8v*)&khi[ln15 * 264 + ks * 32 + qw * 8];
      s8v blo0 = *(const s8v*)&klo[ln15 * 264 + ks * 32 + qw * 8];
      s8v bhi1 = *(const s8v*)&khi[(16 + ln15) * 264 + ks * 32 + qw * 8];
      s8v blo1 = *(const s8v*)&klo[(16 + ln15) * 264 + ks * 32 + qw * 8];
      acc0 = __builtin_amdgcn_mfma_f32_16x16x32_bf16(ahi, bhi0, acc0, 0, 0, 0);
      acc0 = __builtin_amdgcn_mfma_f32_16x16x32_bf16(ahi, blo0, acc0, 0, 0, 0);
      acc0 = __builtin_amdgcn_mfma_f32_16x16x32_bf16(alo, bhi0, acc0, 0, 0, 0);
      acc1 = __builtin_amdgcn_mfma_f32_16x16x32_bf16(ahi, bhi1, acc1, 0, 0, 0);
      acc1 = __builtin_amdgcn_mfma_f32_16x16x32_bf16(ahi, blo1, acc1, 0, 0, 0);
      acc1 = __builtin_amdgcn_mfma_f32_16x16x32_bf16(alo, bhi1, acc1, 0, 0, 0);
    }
    long abase = ((long)bh * NCHUNK + c) * 1024;
#pragma unroll
    for (int r = 0; r < 4; ++r) {
      int i = mt * 16 + qw * 4 + r;
      int j0 = ln15, j1 = 16 + ln15;
      attnb16[abase + i * 32 + j0] = __float2bfloat16(j0 <= i ? acc0[r] : 0.f);
      attnb16[abase + i * 32 + j1] = __float2bfloat16(j1 <= i ? acc1[r] : 0.f);
    }
  }
  __syncthreads();

  if (t < 32) {
    const int l = t;
    for (int i = 1; i < 32; ++i) {
      float s = 0.f;
      for (int j = 0; j < i; ++j) s = fmaf(T[i][j], T[j][l], s);
      T[i][l] += s;
    }
    for (int i = 0; i < 32; ++i) {
      float val = T[i][l] + (i == l ? 1.f : 0.f);
      T[i][l] = val * bet[l];
    }
  }
  __syncthreads();

  {
    const int d = t;
    float acc[32];
#pragma unroll
    for (int i = 0; i < 32; ++i) acc[i] = 0.f;
    for (int j = 0; j < 32; ++j) {
      float vv = v[((long)(b * SEQ + l0 + j)) * DMODEL + h * DHEAD + d];
#pragma unroll
      for (int i = 0; i < 32; ++i) acc[i] = fmaf(T[i][j], vv, acc[i]);
    }
    long ubase = ((long)bh * SEQ + l0) * DHEAD + d;
#pragma unroll
    for (int i = 0; i < 32; ++i) u[ubase + (long)i * DHEAD] = acc[i];
#pragma unroll
    for (int i = 0; i < 32; ++i) acc[i] = 0.f;
    for (int j = 0; j < 32; ++j) {
      float kv = b2f((unsigned short)khi[j * 264 + d]) + b2f((unsigned short)klo[j * 264 + d]);
#pragma unroll
      for (int i = 0; i < 32; ++i) acc[i] = fmaf(T[i][j], kv, acc[i]);
    }
#pragma unroll
    for (int i = 0; i < 32; ++i) wb16[ubase + (long)i * DHEAD] = __float2bfloat16(acc[i]);
  }

  {
    const int s = t;
    unsigned short* kb = (unsigned short*)kTb16 + ((long)bh * NCHUNK + c) * 8192 + (long)s * 32;
#pragma unroll
    for (int i4 = 0; i4 < 8; ++i4) {
      ushort4 pk;
      pk.x = (unsigned short)khi[(i4 * 4 + 0) * 264 + s];
      pk.y = (unsigned short)khi[(i4 * 4 + 1) * 264 + s];
      pk.z = (unsigned short)khi[(i4 * 4 + 2) * 264 + s];
      pk.w = (unsigned short)khi[(i4 * 4 + 3) * 264 + s];
      *(ushort4*)(kb + i4 * 4) = pk;
    }
  }
}

/* ---------- phase B v6: 128 single-wave blocks; pipelined S^T pack
   (pack+read issued right after S-update, latency hidden under o-phase +
   prefetch; no explicit waits — DS FIFO orders write->read). ---------- */
__global__ __launch_bounds__(64, 1) void phaseB(
    const __hip_bfloat16* __restrict__ qpk, const __hip_bfloat16* __restrict__ wb,
    const __hip_bfloat16* __restrict__ kTb, const __hip_bfloat16* __restrict__ attnb,
    const float* __restrict__ u, float* __restrict__ delta) {
  __shared__ __align__(16) short St[16 * 264];
  const int bid = blockIdx.x;
  const int slice = bid & 15;
  const int bh = bid >> 4;
  const int d0 = slice * 16;
  const int t = threadIdx.x; /* 0..63 */
  const int ln15 = t & 15;
  const int qw = t >> 4;

  const short* wbase = (const short*)wb + (long)bh * SEQ * 256;
  const short* qbase = (const short*)qpk + (long)bh * SEQ * 256;
  const short* kTbase = (const short*)kTb + (long)bh * NCHUNK * 8192;
  const short* atbase = (const short*)attnb + (long)bh * NCHUNK * 1024;
  const float* ubase = u + (long)bh * SEQ * 256;
  float* dbase = delta + (long)bh * SEQ * 256;

  f4v Sacc[16];
#pragma unroll
  for (int kt = 0; kt < 16; ++kt) Sacc[kt] = (f4v){0.f, 0.f, 0.f, 0.f};

  s8v wA[2][8], kA[16], atv[2];
  float uf[2][4];
  {
#pragma unroll
    for (int mt = 0; mt < 2; ++mt)
#pragma unroll
      for (int ks = 0; ks < 8; ++ks)
        wA[mt][ks] = *(const s8v*)(wbase + (long)(mt * 16 + ln15) * 256 + ks * 32 + qw * 8);
#pragma unroll
    for (int kt = 0; kt < 16; ++kt)
      kA[kt] = *(const s8v*)(kTbase + (kt * 16 + ln15) * 32 + qw * 8);
#pragma unroll
    for (int mt = 0; mt < 2; ++mt) {
      atv[mt] = *(const s8v*)(atbase + (mt * 16 + ln15) * 32 + qw * 8);
#pragma unroll
      for (int r = 0; r < 4; ++r)
        uf[mt][r] = ubase[(long)(mt * 16 + qw * 4 + r) * 256 + d0 + ln15];
    }
  }

  const int idx0 = (((qw & 1) * 2) * 16 + ln15) * 4;
  const int idx1 = (((qw & 1) * 2 + 1) * 16 + ln15) * 4;
  const bool hiHalf = (qw >= 2);

  /* bS holds S^T B-fragments for the CURRENT chunk; S=0 at c=0 */
  s8v bS[8];
#pragma unroll
  for (int ks = 0; ks < 8; ++ks) bS[ks] = (s8v){0, 0, 0, 0, 0, 0, 0, 0};

  for (int c = 0; c < NCHUNK; ++c) {
    const int l0 = c * 32;

    /* qA loads for this chunk (global; consumed at the o-phase) */
    s8v qA[2][8];
#pragma unroll
    for (int mt = 0; mt < 2; ++mt)
#pragma unroll
      for (int ks = 0; ks < 8; ++ks)
        qA[mt][ks] = *(const s8v*)(qbase + (long)(l0 + mt * 16 + ln15) * 256 + ks * 32 + qw * 8);

    /* (1) dw = w @ S, split chains */
    f4v dwa0 = (f4v){0.f,0.f,0.f,0.f}, dwb0 = (f4v){0.f,0.f,0.f,0.f};
    f4v dwa1 = (f4v){0.f,0.f,0.f,0.f}, dwb1 = (f4v){0.f,0.f,0.f,0.f};
#pragma unroll
    for (int ks = 0; ks < 4; ++ks) {
      dwa0 = __builtin_amdgcn_mfma_f32_16x16x32_bf16(wA[0][ks], bS[ks], dwa0, 0, 0, 0);
      dwa1 = __builtin_amdgcn_mfma_f32_16x16x32_bf16(wA[1][ks], bS[ks], dwa1, 0, 0, 0);
      dwb0 = __builtin_amdgcn_mfma_f32_16x16x32_bf16(wA[0][ks + 4], bS[ks + 4], dwb0, 0, 0, 0);
      dwb1 = __builtin_amdgcn_mfma_f32_16x16x32_bf16(wA[1][ks + 4], bS[ks + 4], dwb1, 0, 0, 0);
    }
    float u2a[4], u2b[4];
#pragma unroll
    for (int r = 0; r < 4; ++r) {
      u2a[r] = uf[0][r] - (dwa0[r] + dwb0[r]);
      u2b[r] = uf[1][r] - (dwa1[r] + dwb1[r]);
    }
    /* (2) u2^T redistribute via ds_bpermute */
    s8v bu;
    {
      int A0 = (int)pk2(u2a[0], u2a[1]);
      int A1 = (int)pk2(u2a[2], u2a[3]);
      int B0 = (int)pk2(u2b[0], u2b[1]);
      int B1 = (int)pk2(u2b[2], u2b[3]);
      int p0a = __builtin_amdgcn_ds_bpermute(idx0, A0);
      int p0b = __builtin_amdgcn_ds_bpermute(idx0, B0);
      int p1a = __builtin_amdgcn_ds_bpermute(idx0, A1);
      int p1b = __builtin_amdgcn_ds_bpermute(idx0, B1);
      int p2a = __builtin_amdgcn_ds_bpermute(idx1, A0);
      int p2b = __builtin_amdgcn_ds_bpermute(idx1, B0);
      int p3a = __builtin_amdgcn_ds_bpermute(idx1, A1);
      int p3b = __builtin_amdgcn_ds_bpermute(idx1, B1);
      int4 buw = make_int4(hiHalf ? p0b : p0a, hiHalf ? p1b : p1a,
                           hiHalf ? p2b : p2a, hiHalf ? p3b : p3a);
      bu = *(s8v*)&buw;
    }

    /* (3) attn part of o */
    f4v oA0 = __builtin_amdgcn_mfma_f32_16x16x32_bf16(atv[0], bu, (f4v){0.f,0.f,0.f,0.f}, 0, 0, 0);
    f4v oA1 = __builtin_amdgcn_mfma_f32_16x16x32_bf16(atv[1], bu, (f4v){0.f,0.f,0.f,0.f}, 0, 0, 0);

    /* (4) recurrence: S += kT @ u2 */
#pragma unroll
    for (int kt = 0; kt < 16; ++kt)
      Sacc[kt] = __builtin_amdgcn_mfma_f32_16x16x32_bf16(kA[kt], bu, Sacc[kt], 0, 0, 0);

    s8v bSn[8];
    if (c + 1 < NCHUNK) {
      /* (5) pack NEW S^T to LDS and immediately issue reads; DS FIFO orders
         write->read, latency hides under (6)+(7). */
#pragma unroll
      for (int kt = 0; kt < 16; ++kt) {
        ushort4 pk;
        pk.x = f2b(Sacc[kt][0]); pk.y = f2b(Sacc[kt][1]);
        pk.z = f2b(Sacc[kt][2]); pk.w = f2b(Sacc[kt][3]);
        *(ushort4*)&St[ln15 * 264 + kt * 16 + qw * 4] = pk;
      }
#pragma unroll
      for (int ks = 0; ks < 8; ++ks)
        bSn[ks] = *(const s8v*)&St[ln15 * 264 + ks * 32 + qw * 8];

      /* (6) prefetch chunk c+1 operands */
      const int ln = l0 + 32;
#pragma unroll
      for (int mt = 0; mt < 2; ++mt)
#pragma unroll
        for (int ks = 0; ks < 8; ++ks)
          wA[mt][ks] = *(const s8v*)(wbase + (long)(ln + mt * 16 + ln15) * 256 + ks * 32 + qw * 8);
#pragma unroll
      for (int kt = 0; kt < 16; ++kt)
        kA[kt] = *(const s8v*)(kTbase + (long)(c + 1) * 8192 + (kt * 16 + ln15) * 32 + qw * 8);
#pragma unroll
      for (int mt = 0; mt < 2; ++mt) {
        atv[mt] = *(const s8v*)(atbase + (long)(c + 1) * 1024 + (mt * 16 + ln15) * 32 + qw * 8);
#pragma unroll
        for (int r = 0; r < 4; ++r)
          uf[mt][r] = ubase[(long)(ln + mt * 16 + qw * 4 + r) * 256 + d0 + ln15];
      }
    }

    /* (7) o += q @ S (pre-update S, from bS regs) */
    f4v oB0 = (f4v){0.f,0.f,0.f,0.f}, oB1 = (f4v){0.f,0.f,0.f,0.f};
#pragma unroll
    for (int ks = 0; ks < 4; ++ks) {
      oA0 = __builtin_amdgcn_mfma_f32_16x16x32_bf16(qA[0][ks], bS[ks], oA0, 0, 0, 0);
      oA1 = __builtin_amdgcn_mfma_f32_16x16x32_bf16(qA[1][ks], bS[ks], oA1, 0, 0, 0);
      oB0 = __builtin_amdgcn_mfma_f32_16x16x32_bf16(qA[0][ks + 4], bS[ks + 4], oB0, 0, 0, 0);
      oB1 = __builtin_amdgcn_mfma_f32_16x16x32_bf16(qA[1][ks + 4], bS[ks + 4], oB1, 0, 0, 0);
    }
#pragma unroll
    for (int r = 0; r < 4; ++r) {
      dbase[(long)(l0 + qw * 4 + r) * 256 + d0 + ln15] = oA0[r] + oB0[r];
      dbase[(long)(l0 + 16 + qw * 4 + r) * 256 + d0 + ln15] = oA1[r] + oB1[r];
    }
    if (c + 1 < NCHUNK) {
#pragma unroll
      for (int ks = 0; ks < 8; ++ks) bS[ks] = bSn[ks];
    }
  }
}

/* ---------- FIR v2: transposed [tap][ch] filters, coalesced ---------- */
__global__ __launch_bounds__(256) void fir_kernel(
    const float* __restrict__ v, const float* __restrict__ fsT,
    const float* __restrict__ flT, float* __restrict__ fs, float* __restrict__ fl) {
  const int row = blockIdx.x;
  const int l = row & (SEQ - 1);
  const int t = threadIdx.x;
  const int cb = t * 4;
  float4 accl = make_float4(0, 0, 0, 0);
  float4 accs = make_float4(0, 0, 0, 0);
  const float* vb = v + (long)(row - 30) * DMODEL + cb;
  if (l >= 30) {
#pragma unroll
    for (int j = 0; j < 31; ++j) {
      float4 w4 = *(const float4*)(flT + j * DMODEL + cb);
      float4 xv = *(const float4*)(vb + (long)j * DMODEL);
      accl.x = fmaf(w4.x, xv.x, accl.x);
      accl.y = fmaf(w4.y, xv.y, accl.y);
      accl.z = fmaf(w4.z, xv.z, accl.z);
      accl.w = fmaf(w4.w, xv.w, accl.w);
      if (j >= 28) {
        float4 s4 = *(const float4*)(fsT + (j - 28) * DMODEL + cb);
        accs.x = fmaf(s4.x, xv.x, accs.x);
        accs.y = fmaf(s4.y, xv.y, accs.y);
        accs.z = fmaf(s4.z, xv.z, accs.z);
        accs.w = fmaf(s4.w, xv.w, accs.w);
      }
    }
  } else {
    for (int j = 30 - l; j < 31; ++j) {
      float4 w4 = *(const float4*)(flT + j * DMODEL + cb);
      float4 xv = *(const float4*)(vb + (long)j * DMODEL);
      accl.x = fmaf(w4.x, xv.x, accl.x);
      accl.y = fmaf(w4.y, xv.y, accl.y);
      accl.z = fmaf(w4.z, xv.z, accl.z);
      accl.w = fmaf(w4.w, xv.w, accl.w);
      if (j >= 28) {
        float4 s4 = *(const float4*)(fsT + (j - 28) * DMODEL + cb);
        accs.x = fmaf(s4.x, xv.x, accs.x);
        accs.y = fmaf(s4.y, xv.y, accs.y);
        accs.z = fmaf(s4.z, xv.z, accs.z);
        accs.w = fmaf(s4.w, xv.w, accs.w);
      }
    }
  }
  *(float4*)(fs + (long)row * DMODEL + cb) = accs;
  *(float4*)(fl + (long)row * DMODEL + cb) = accl;
}

/* ---------- logits from bf16 hmid ; p = softmax(logits/tau)*0.925+0.025 ---------- */
__global__ __launch_bounds__(256) void router_logits(
    const __hip_bfloat16* __restrict__ hmid, const float* __restrict__ Wr2,
    const float* __restrict__ br2, const float* __restrict__ ltg, float* __restrict__ p) {
  const int row = blockIdx.x;
  const int t = threadIdx.x;
  float acc[12];
#pragma unroll
  for (int j = 0; j < 12; ++j) acc[j] = 0.f;
  const __hip_bfloat16* hr = hmid + (long)row * 2048;
  for (int k = t; k < 2048; k += 256) {
    float hv = __bfloat162float(hr[k]);
    const float* wr = Wr2 + k * 12;
#pragma unroll
    for (int j = 0; j < 12; ++j) acc[j] = fmaf(hv, wr[j], acc[j]);
  }
#pragma unroll
  for (int m = 1; m < 64; m <<= 1)
#pragma unroll
    for (int j = 0; j < 12; ++j) acc[j] += __shfl_xor(acc[j], m);
  __shared__ float red[4][12];
  if ((t & 63) == 0) {
    int wv = t >> 6;
#pragma unroll
    for (int j = 0; j < 12; ++j) red[wv][j] = acc[j];
  }
  __syncthreads();
  if (t < 4) {
    const int h = t;
    float l3[3];
#pragma unroll
    for (int j = 0; j < 3; ++j) {
      int col = h * 3 + j;
      l3[j] = red[0][col] + red[1][col] + red[2][col] + red[3][col] + br2[col];
    }
    float inv_tau = expf(-ltg[h >> 1]);
    float y0 = l3[0] * inv_tau, y1 = l3[1] * inv_tau, y2 = l3[2] * inv_tau;
    float mx = fmaxf(y0, fmaxf(y1, y2));
    float e0 = expf(y0 - mx), e1 = expf(y1 - mx), e2 = expf(y2 - mx);
    float inv = 1.f / (e0 + e1 + e2);
    p[(long)row * 12 + h * 3 + 0] = e0 * inv * 0.925f + 0.025f;
    p[(long)row * 12 + h * 3 + 1] = e1 * inv * 0.925f + 0.025f;
    p[(long)row * 12 + h * 3 + 2] = e2 * inv * 0.925f + 0.025f;
  }
}

/* ---------- mixture + identity + RMS norm -> bf16 out. ---------- */
__global__ __launch_bounds__(256) void omix(
    const float* __restrict__ fs, const float* __restrict__ fl,
    const float* __restrict__ dl, const float* __restrict__ vh,
    const float* __restrict__ p, const float* __restrict__ idsc,
    const float* __restrict__ onw, __hip_bfloat16* __restrict__ o) {
  const int row = blockIdx.x;
  const int b = row >> 12;
  const int l = row & (SEQ - 1);
  const int t = threadIdx.x;
  const int h = t >> 6;
  const int lane = t & 63;
  const long base = (long)row * DMODEL + h * DHEAD + lane * 4;
  const long dbase = ((long)(b * NH + h) * SEQ + l) * DHEAD + lane * 4;
  float p0 = p[(long)row * 12 + h * 3 + 0];
  float p1 = p[(long)row * 12 + h * 3 + 1];
  float p2 = p[(long)row * 12 + h * 3 + 2];
  float idv = idsc[(long)row * NH + h];
  float4 a = *(const float4*)(fs + base);
  float4 bq = *(const float4*)(fl + base);
  float4 cq = *(const float4*)(dl + dbase);
  float4 vv = *(const float4*)(vh + base);
  float4 ov;
  ov.x = p0 * a.x + p1 * bq.x + p2 * cq.x + idv * vv.x;
  ov.y = p0 * a.y + p1 * bq.y + p2 * cq.y + idv * vv.y;
  ov.z = p0 * a.z + p1 * bq.z + p2 * cq.z + idv * vv.z;
  ov.w = p0 * a.w + p1 * bq.w + p2 * cq.w + idv * vv.w;
  float ss = ov.x * ov.x + ov.y * ov.y + ov.z * ov.z + ov.w * ov.w;
#pragma unroll
  for (int m = 1; m < 64; m <<= 1) ss += __shfl_xor(ss, m);
  float rms = rsqrtf(ss * (1.f / 256.f) + 1e-5f);
  float4 wn = *(const float4*)(onw + lane * 4);
  __hip_bfloat16 tmp[4] = {__float2bfloat16(ov.x * rms * wn.x),
                           __float2bfloat16(ov.y * rms * wn.y),
                           __float2bfloat16(ov.z * rms * wn.z),
                           __float2bfloat16(ov.w * rms * wn.w)};
  *(ushort4*)(o + base) = *(ushort4*)tmp;
}

extern "C" void kernel_launch(void* const* d_in, const int* in_sizes, int n_in,
                              void* d_out, int out_size, void* d_ws, size_t ws_size,
                              hipStream_t stream) {
  const float* x = (const float*)d_in[0];
  const float* Wq = (const float*)d_in[1];
  const float* Wk = (const float*)d_in[2];
  const float* Wv = (const float*)d_in[3];
  const float* Wb = (const float*)d_in[4];
  const float* conv_q = (const float*)d_in[5];
  const float* conv_k = (const float*)d_in[6];
  const float* conv_v = (const float*)d_in[7];
  const float* fir_s = (const float*)d_in[8];
  const float* fir_l = (const float*)d_in[9];
  const float* alpha_id = (const float*)d_in[10];
  const float* Wid = (const float*)d_in[11];
  const float* bidp = (const float*)d_in[12];
  const float* Wr1 = (const float*)d_in[13];
  const float* br1 = (const float*)d_in[14];
  const float* Wr2 = (const float*)d_in[15];
  const float* br2 = (const float*)d_in[16];
  const float* ltg = (const float*)d_in[17];
  const float* onw = (const float*)d_in[19];
  const float* Wo = (const float*)d_in[20];

  float* ws = (float*)d_ws;
  float* pre = ws + 0;
  float* ubuf = ws + 8388608;
  float* wbuf = ws + 16777216;
  float* attnbuf = ws + 25165824;
  float* qbuf = ws + 26214400;
  float* kbuf = ws + 34603008;
  float* vbuf = ws + 42991616;
  float* betabuf = ws + 51380224;
  float* idscbuf = ws + 51412992;
  float* pbuf = ws + 51445760;
  float* flTb = ws + 51544064;  /* 31*1024 */
  float* fsTb = ws + 51575808;  /* 3*1024, end 51578880 (~206.3 MB) */
  float* deltabuf = ubuf;
  __hip_bfloat16* xb = (__hip_bfloat16*)ubuf;
  __hip_bfloat16* Wqt = (__hip_bfloat16*)(wbuf);
  __hip_bfloat16* Wkt = (__hip_bfloat16*)(wbuf + 524288);
  __hip_bfloat16* Wvt = (__hip_bfloat16*)(wbuf + 1048576);
  __hip_bfloat16* wb16 = (__hip_bfloat16*)wbuf;
  __hip_bfloat16* kTb16 = (__hip_bfloat16*)wbuf + 8388608;
  __hip_bfloat16* attnb16 = (__hip_bfloat16*)attnbuf;
  __hip_bfloat16* qpk16 = (__hip_bfloat16*)pre;
  __hip_bfloat16* rinb = (__hip_bfloat16*)(wbuf);
  __hip_bfloat16* Wr1t = (__hip_bfloat16*)(wbuf + 4325376);
  __hip_bfloat16* Wot = (__hip_bfloat16*)(wbuf + 5406720);
  __hip_bfloat16* omixb = (__hip_bfloat16*)(wbuf);
  __hip_bfloat16* hmid = (__hip_bfloat16*)pre;
  float* fsb = qbuf;
  float* flb = kbuf;

  dim3 blk(256);
  head_fused<<<dim3(11298), blk, 0, stream>>>(x, xb, Wb, Wid, alpha_id, bidp,
      betabuf, idscbuf, Wq, Wqt, Wk, Wkt, Wv, Wvt, fir_s, fir_l, fsTb, flTb);
  gemm_bf16<0, false><<<dim3(8, 64), blk, 0, stream>>>(xb, Wqt, nullptr, pre, ROWS, 1024, 1024);
  conv_silu<1><<<dim3(ROWS), blk, 0, stream>>>(pre, conv_q, qbuf);
  gemm_bf16<0, false><<<dim3(8, 64), blk, 0, stream>>>(xb, Wkt, nullptr, pre, ROWS, 1024, 1024);
  conv_silu<1><<<dim3(ROWS), blk, 0, stream>>>(pre, conv_k, kbuf);
  gemm_bf16<0, false><<<dim3(8, 64), blk, 0, stream>>>(xb, Wvt, nullptr, pre, ROWS, 1024, 1024);
  conv_silu<0><<<dim3(ROWS), blk, 0, stream>>>(pre, conv_v, vbuf);
  phaseA<<<dim3(BATCH * NH * NCHUNK), blk, 0, stream>>>(qbuf, kbuf, vbuf, betabuf, ubuf, wb16, kTb16, attnb16, qpk16);
  phaseB<<<dim3(BATCH * NH * 16), dim3(64), 0, stream>>>(qpk16, wb16, kTb16, attnb16, ubuf, deltabuf);
  fir_kernel<<<dim3(ROWS), blk, 0, stream>>>(vbuf, fsTb, flTb, fsb, flb);
  stats_tcast<<<dim3(11328), blk, 0, stream>>>(x, fsb, flb, deltabuf, rinb, Wr1, Wr1t, Wo, Wot);
  gemm_bf16<1, true><<<dim3(16, 64), blk, 0, stream>>>(rinb, Wr1t, br1, hmid, ROWS, 2048, 1056);
  router_logits<<<dim3(ROWS), blk, 0, stream>>>(hmid, Wr2, br2, ltg, pbuf);
  omix<<<dim3(ROWS), blk, 0, stream>>>(fsb, flb, deltabuf, vbuf, pbuf, idscbuf, onw, omixb);
  gemm_bf16<0, false><<<dim3(8, 64), blk, 0, stream>>>(omixb, Wot, nullptr, d_out, ROWS, 1024, 1024);
}

// Round 5
// 805.636 us; speedup vs baseline: 1.4569x; 1.1218x over previous
//
#include <hip/hip_runtime.h>
#include <hip/hip_bf16.h>
#include <math.h>

#define BATCH 2
#define SEQ 4096
#define DMODEL 1024
#define NH 4
#define DHEAD 256
#define NCHUNK 128
#define ROWS (BATCH * SEQ) /* 8192 */

typedef short s8v __attribute__((ext_vector_type(8)));   /* 8 bf16 in 4 VGPRs */
typedef float f4v __attribute__((ext_vector_type(4)));

__device__ __forceinline__ float sigm(float x) { return 1.0f / (1.0f + expf(-x)); }
__device__ __forceinline__ float siluf(float x) { return x / (1.0f + expf(-x)); }
__device__ __forceinline__ unsigned short f2b(float f) {
  __hip_bfloat16 h = __float2bfloat16(f);
  return *(unsigned short*)&h;
}
__device__ __forceinline__ float b2f(unsigned short u) {
  __hip_bfloat16 h = *(__hip_bfloat16*)&u;
  return __bfloat162float(h);
}
__device__ __forceinline__ void gload16(const short* g, short* l) {
  __builtin_amdgcn_global_load_lds(
      (const __attribute__((address_space(1))) unsigned int*)(const void*)g,
      (__attribute__((address_space(3))) unsigned int*)(void*)l, 16, 0, 0);
}

/* ================= device bodies for fused head/tail kernels ================= */

__device__ __forceinline__ void prep_body(
    const float* __restrict__ x, __hip_bfloat16* __restrict__ xb,
    const float* __restrict__ Wb, const float* __restrict__ Wid,
    const float* __restrict__ alpha_id, const float* __restrict__ bidp,
    float* __restrict__ beta, float* __restrict__ idsc, int row,
    float (*red)[8]) {
  const int t = threadIdx.x;
  const long base = (long)row * DMODEL + t * 4;
  float4 xv = *(const float4*)(x + base);
  {
    __hip_bfloat16 tmp[4] = {__float2bfloat16(xv.x), __float2bfloat16(xv.y),
                             __float2bfloat16(xv.z), __float2bfloat16(xv.w)};
    *(ushort4*)(xb + base) = *(ushort4*)tmp;
  }
  float xa[4] = {xv.x, xv.y, xv.z, xv.w};
  float ab[4] = {0, 0, 0, 0}, ai[4] = {0, 0, 0, 0};
#pragma unroll
  for (int i = 0; i < 4; ++i) {
    int k = t * 4 + i;
    float4 wb4 = *(const float4*)(Wb + k * 4);
    float4 wi4 = *(const float4*)(Wid + k * 4);
    ab[0] = fmaf(xa[i], wb4.x, ab[0]); ab[1] = fmaf(xa[i], wb4.y, ab[1]);
    ab[2] = fmaf(xa[i], wb4.z, ab[2]); ab[3] = fmaf(xa[i], wb4.w, ab[3]);
    ai[0] = fmaf(xa[i], wi4.x, ai[0]); ai[1] = fmaf(xa[i], wi4.y, ai[1]);
    ai[2] = fmaf(xa[i], wi4.z, ai[2]); ai[3] = fmaf(xa[i], wi4.w, ai[3]);
  }
#pragma unroll
  for (int m = 1; m < 64; m <<= 1) {
#pragma unroll
    for (int hh = 0; hh < 4; ++hh) {
      ab[hh] += __shfl_xor(ab[hh], m);
      ai[hh] += __shfl_xor(ai[hh], m);
    }
  }
  if ((t & 63) == 0) {
    int wv = t >> 6;
#pragma unroll
    for (int hh = 0; hh < 4; ++hh) {
      red[wv][hh] = ab[hh];
      red[wv][4 + hh] = ai[hh];
    }
  }
  __syncthreads();
  if (t < 8) {
    float s = red[0][t] + red[1][t] + red[2][t] + red[3][t];
    if (t < 4) {
      beta[(long)row * NH + t] = sigm(s);
    } else {
      int hh = t - 4;
      idsc[(long)row * NH + hh] = 0.06f + sigm(alpha_id[hh]) * sigm(s + bidp[hh]);
    }
  }
}

__device__ __forceinline__ void tcast_body(
    const float* __restrict__ W, __hip_bfloat16* __restrict__ Wt,
    int K, int N, int Ks, int bx, int by, float (*tile)[33]) {
  const int t = threadIdx.x;
  const int tx = t & 31, ty = t >> 5;
  const int kb = by * 32, nb = bx * 32;
#pragma unroll
  for (int r = 0; r < 4; ++r) {
    int kk = kb + ty + 8 * r;
    tile[ty + 8 * r][tx] = (kk < K) ? W[(long)kk * N + nb + tx] : 0.f;
  }
  __syncthreads();
#pragma unroll
  for (int r = 0; r < 4; ++r) {
    Wt[(long)(nb + ty + 8 * r) * Ks + kb + tx] = __float2bfloat16(tile[tx][ty + 8 * r]);
  }
}

__device__ __forceinline__ void firT_body(
    const float* __restrict__ fshort, const float* __restrict__ flong,
    float* __restrict__ fsT, float* __restrict__ flT, int j) {
  const int t = threadIdx.x;
  if (j < 31) {
#pragma unroll
    for (int i = 0; i < 4; ++i) {
      int c = t * 4 + i;
      flT[j * 1024 + c] = flong[c * 31 + j];
    }
  } else {
    int tp = j - 31;
#pragma unroll
    for (int i = 0; i < 4; ++i) {
      int c = t * 4 + i;
      fsT[tp * 1024 + c] = fshort[c * 3 + tp];
    }
  }
}

__device__ __forceinline__ void stats_body(
    const float* __restrict__ x, const float* __restrict__ fs,
    const float* __restrict__ fl, const float* __restrict__ dl,
    __hip_bfloat16* __restrict__ rinb, int row) {
  const int b = row >> 12;
  const int l = row & (SEQ - 1);
  const int t = threadIdx.x;
  float4 xv = *(const float4*)(x + (long)row * DMODEL + t * 4);
  {
    __hip_bfloat16 tmp[4] = {__float2bfloat16(xv.x), __float2bfloat16(xv.y),
                             __float2bfloat16(xv.z), __float2bfloat16(xv.w)};
    *(ushort4*)(rinb + (long)row * 1056 + t * 4) = *(ushort4*)tmp;
  }
  if (t < 8) rinb[(long)row * 1056 + 1048 + t] = __float2bfloat16(0.f);
  const int h = t >> 6;
  const int lane = t & 63;
  const long base = (long)row * DMODEL + h * DHEAD + lane * 4;
  const long dbase = ((long)(b * NH + h) * SEQ + l) * DHEAD + lane * 4;
  float4 a = *(const float4*)(fs + base);
  float4 bq = *(const float4*)(fl + base);
  float4 cq = *(const float4*)(dl + dbase);
  float s[6];
  s[0] = a.x + a.y + a.z + a.w;
  s[1] = a.x * a.x + a.y * a.y + a.z * a.z + a.w * a.w;
  s[2] = bq.x + bq.y + bq.z + bq.w;
  s[3] = bq.x * bq.x + bq.y * bq.y + bq.z * bq.z + bq.w * bq.w;
  s[4] = cq.x + cq.y + cq.z + cq.w;
  s[5] = cq.x * cq.x + cq.y * cq.y + cq.z * cq.z + cq.w * cq.w;
#pragma unroll
  for (int m = 1; m < 64; m <<= 1)
#pragma unroll
    for (int j = 0; j < 6; ++j) s[j] += __shfl_xor(s[j], m);
  if (lane == 0) {
    __hip_bfloat16* rb = rinb + (long)row * 1056 + 1024;
    float m0 = s[0] * (1.f / 256.f);
    float m1 = s[2] * (1.f / 256.f);
    float m2 = s[4] * (1.f / 256.f);
    rb[h] = __float2bfloat16(m0);
    rb[4 + h] = __float2bfloat16(sqrtf(fmaxf(s[1] * (1.f / 256.f) - m0 * m0, 0.f)));
    rb[8 + h] = __float2bfloat16(m1);
    rb[12 + h] = __float2bfloat16(sqrtf(fmaxf(s[3] * (1.f / 256.f) - m1 * m1, 0.f)));
    rb[16 + h] = __float2bfloat16(m2);
    rb[20 + h] = __float2bfloat16(sqrtf(fmaxf(s[5] * (1.f / 256.f) - m2 * m2, 0.f)));
  }
}

/* ================= fused head/tail kernels ================= */

__global__ __launch_bounds__(256) void head_fused(
    const float* __restrict__ x, __hip_bfloat16* __restrict__ xb,
    const float* __restrict__ Wb, const float* __restrict__ Wid,
    const float* __restrict__ alpha_id, const float* __restrict__ bidp,
    float* __restrict__ beta, float* __restrict__ idsc,
    const float* __restrict__ Wq, __hip_bfloat16* __restrict__ Wqt,
    const float* __restrict__ Wk, __hip_bfloat16* __restrict__ Wkt,
    const float* __restrict__ Wv, __hip_bfloat16* __restrict__ Wvt,
    const float* __restrict__ fir_s, const float* __restrict__ fir_l,
    float* __restrict__ fsT, float* __restrict__ flT) {
  __shared__ float tile[32][33];
  __shared__ float red[4][8];
  const int bid = blockIdx.x;
  if (bid < 8192) {
    prep_body(x, xb, Wb, Wid, alpha_id, bidp, beta, idsc, bid, red);
  } else if (bid < 9216) {
    int r = bid - 8192;
    tcast_body(Wq, Wqt, 1024, 1024, 1024, r & 31, r >> 5, tile);
  } else if (bid < 10240) {
    int r = bid - 9216;
    tcast_body(Wk, Wkt, 1024, 1024, 1024, r & 31, r >> 5, tile);
  } else if (bid < 11264) {
    int r = bid - 10240;
    tcast_body(Wv, Wvt, 1024, 1024, 1024, r & 31, r >> 5, tile);
  } else {
    firT_body(fir_s, fir_l, fsT, flT, bid - 11264);
  }
}

__global__ __launch_bounds__(256) void stats_tcast(
    const float* __restrict__ x, const float* __restrict__ fs,
    const float* __restrict__ fl, const float* __restrict__ dl,
    __hip_bfloat16* __restrict__ rinb,
    const float* __restrict__ Wr1, __hip_bfloat16* __restrict__ Wr1t,
    const float* __restrict__ Wo, __hip_bfloat16* __restrict__ Wot) {
  __shared__ float tile[32][33];
  const int bid = blockIdx.x;
  if (bid < 8192) {
    stats_body(x, fs, fl, dl, rinb, bid);
  } else if (bid < 10304) {
    int r = bid - 8192;
    tcast_body(Wr1, Wr1t, 1048, 2048, 1056, r & 63, r >> 6, tile);
  } else {
    int r = bid - 10304;
    tcast_body(Wo, Wot, 1024, 1024, 1024, r & 31, r >> 5, tile);
  }
}

/* ---------------- bf16 MFMA GEMM with global_load_lds staging + XCD swizzle ---------------- */
template <int ACT, bool BF16OUT>
__global__ __launch_bounds__(256) void gemm_bf16(
    const __hip_bfloat16* __restrict__ A, const __hip_bfloat16* __restrict__ Bt,
    const float* __restrict__ bias, void* __restrict__ Cv,
    int M, int N, int Ks) {
  __shared__ short As[128 * 32];
  __shared__ short Bs[128 * 32];
  const int t = threadIdx.x;
  const int wv = t >> 6;
  const int lane = t & 63;
  const int nx = gridDim.x;
  int flat = blockIdx.y * nx + blockIdx.x;
  const int q8 = (nx * gridDim.y) >> 3;
  flat = (flat & 7) * q8 + (flat >> 3);
  const int row0 = (flat / nx) * 128, col0 = (flat % nx) * 128;
  const int mq = (wv >> 1) * 64, nq = (wv & 1) * 64;
  const int ln15 = lane & 15;
  const int kq = (lane >> 4) * 8;
  const int srow = wv * 16 + (lane >> 2);
  const int scol = (lane & 3) * 8;
  const short* Ag0 = (const short*)A + (long)(row0 + srow) * Ks + scol;
  const short* Ag1 = Ag0 + (long)64 * Ks;
  const short* Bg0 = (const short*)Bt + (long)(col0 + srow) * Ks + scol;
  const short* Bg1 = Bg0 + (long)64 * Ks;
  short* Ad0 = &As[(wv * 16) * 32];
  short* Ad1 = &As[(64 + wv * 16) * 32];
  short* Bd0 = &Bs[(wv * 16) * 32];
  short* Bd1 = &Bs[(64 + wv * 16) * 32];

  f4v acc[4][4];
#pragma unroll
  for (int i = 0; i < 4; ++i)
#pragma unroll
    for (int j = 0; j < 4; ++j) acc[i][j] = (f4v){0.f, 0.f, 0.f, 0.f};

  for (int k0 = 0; k0 < Ks; k0 += 32) {
    __syncthreads();
    gload16(Ag0 + k0, Ad0);
    gload16(Ag1 + k0, Ad1);
    gload16(Bg0 + k0, Bd0);
    gload16(Bg1 + k0, Bd1);
    __syncthreads();
    s8v af[4], bf[4];
#pragma unroll
    for (int mt = 0; mt < 4; ++mt)
      af[mt] = *(const s8v*)&As[(mq + mt * 16 + ln15) * 32 + kq];
#pragma unroll
    for (int nt = 0; nt < 4; ++nt)
      bf[nt] = *(const s8v*)&Bs[(nq + nt * 16 + ln15) * 32 + kq];
#pragma unroll
    for (int mt = 0; mt < 4; ++mt)
#pragma unroll
      for (int nt = 0; nt < 4; ++nt)
        acc[mt][nt] = __builtin_amdgcn_mfma_f32_16x16x32_bf16(af[mt], bf[nt], acc[mt][nt], 0, 0, 0);
  }
  const int rbase = (lane >> 4) * 4;
#pragma unroll
  for (int mt = 0; mt < 4; ++mt) {
#pragma unroll
    for (int nt = 0; nt < 4; ++nt) {
      int gcol = col0 + nq + nt * 16 + ln15;
#pragma unroll
      for (int r = 0; r < 4; ++r) {
        int grow = row0 + mq + mt * 16 + rbase + r;
        float v = acc[mt][nt][r];
        if (ACT == 1) {
          v += bias[gcol];
          v = 0.5f * v * (1.0f + erff(v * 0.70710678118654752f));
        }
        if (BF16OUT) {
          ((__hip_bfloat16*)Cv)[(long)grow * N + gcol] = __float2bfloat16(v);
        } else {
          ((float*)Cv)[(long)grow * N + gcol] = v;
        }
      }
    }
  }
}

/* ---------- causal depthwise conv (K=4) + silu; MODE1 adds per-head l2norm ---------- */
template <int MODE>
__global__ __launch_bounds__(256) void conv_silu(
    const float* __restrict__ pre, const float* __restrict__ cw, float* __restrict__ out) {
  const int row = blockIdx.x;
  const int l = row & (SEQ - 1);
  const int t = threadIdx.x;
  const int cb = t * 4;
  float wts[4][4];
#pragma unroll
  for (int cc = 0; cc < 4; ++cc) {
    float4 w4 = *(const float4*)(cw + (cb + cc) * 4);
    wts[cc][0] = w4.x; wts[cc][1] = w4.y; wts[cc][2] = w4.z; wts[cc][3] = w4.w;
  }
  float acc[4] = {0, 0, 0, 0};
#pragma unroll
  for (int tap = 0; tap < 4; ++tap) {
    int lr = l - 3 + tap;
    if (lr >= 0) {
      float4 xv = *(const float4*)(pre + (long)(row - 3 + tap) * DMODEL + cb);
      acc[0] = fmaf(wts[0][tap], xv.x, acc[0]);
      acc[1] = fmaf(wts[1][tap], xv.y, acc[1]);
      acc[2] = fmaf(wts[2][tap], xv.z, acc[2]);
      acc[3] = fmaf(wts[3][tap], xv.w, acc[3]);
    }
  }
#pragma unroll
  for (int i = 0; i < 4; ++i) acc[i] = siluf(acc[i]);
  if (MODE == 1) {
    float ss = acc[0] * acc[0] + acc[1] * acc[1] + acc[2] * acc[2] + acc[3] * acc[3];
#pragma unroll
    for (int m = 1; m < 64; m <<= 1) ss += __shfl_xor(ss, m);
    float rn = rsqrtf(ss + 1e-6f);
#pragma unroll
    for (int i = 0; i < 4; ++i) acc[i] *= rn;
  }
  float4 ov = make_float4(acc[0], acc[1], acc[2], acc[3]);
  *(float4*)(out + (long)row * DMODEL + cb) = ov;
}

/* ---------- phase A v2: MFMA split-bf16 Gram products ---------- */
__global__ __launch_bounds__(256) void phaseA(
    const float* __restrict__ qn, const float* __restrict__ kn, const float* __restrict__ v,
    const float* __restrict__ beta, float* __restrict__ u,
    __hip_bfloat16* __restrict__ wb16, __hip_bfloat16* __restrict__ kTb16,
    __hip_bfloat16* __restrict__ attnb16, __hip_bfloat16* __restrict__ qpk) {
  __shared__ short khi[32 * 264];
  __shared__ short klo[32 * 264];
  __shared__ float T[32][33];
  __shared__ float bet[32];
  const int bid = blockIdx.x;
  const int c = bid & (NCHUNK - 1);
  const int h = (bid >> 7) & 3;
  const int b = bid >> 9;
  const int bh = b * NH + h;
  const int l0 = c * 32;
  const int t = threadIdx.x;
  const int wv = t >> 6;
  const int lane = t & 63;
  const int ln15 = lane & 15;
  const int qw = lane >> 4;

#pragma unroll
  for (int r = 0; r < 8; ++r) {
    int idx = t + 256 * r;
    int i = idx >> 6;
    int f = (idx & 63) * 4;
    float4 kv = *(const float4*)(kn + ((long)(b * SEQ + l0 + i)) * DMODEL + h * DHEAD + f);
    float a[4] = {kv.x, kv.y, kv.z, kv.w};
    ushort4 hi4, lo4;
    unsigned short* hp = (unsigned short*)&hi4;
    unsigned short* lp = (unsigned short*)&lo4;
#pragma unroll
    for (int j = 0; j < 4; ++j) {
      unsigned short hb = f2b(a[j]);
      hp[j] = hb;
      lp[j] = f2b(a[j] - b2f(hb));
    }
    *(ushort4*)&khi[i * 264 + f] = hi4;
    *(ushort4*)&klo[i * 264 + f] = lo4;
  }
  if (t < 32) bet[t] = beta[(long)(b * SEQ + l0 + t) * NH + h];
  __syncthreads();

  if (wv < 2) {
    const int mt = wv;
    f4v acc0 = (f4v){0.f, 0.f, 0.f, 0.f};
    f4v acc1 = (f4v){0.f, 0.f, 0.f, 0.f};
#pragma unroll
    for (int ks = 0; ks < 8; ++ks) {
      s8v ahi = *(const s8v*)&khi[(mt * 16 + ln15) * 264 + ks * 32 + qw * 8];
      s8v alo = *(const s8v*)&klo[(mt * 16 + ln15) * 264 + ks * 32 + qw * 8];
      s8v bhi0 = *(const s8v*)&khi[ln15 * 264 + ks * 32 + qw * 8];
      s8v blo0 = *(const s8v*)&klo[ln15 * 264 + ks * 32 + qw * 8];
      s8v bhi1 = *(const s8v*)&khi[(16 + ln15) * 264 + ks * 32 + qw * 8];
      s8v blo1 = *(const s8v*)&klo[(16 + ln15) * 264 + ks * 32 + qw * 8];
      acc0 = __builtin_amdgcn_mfma_f32_16x16x32_bf16(ahi, bhi0, acc0, 0, 0, 0);
      acc0 = __builtin_amdgcn_mfma_f32_16x16x32_bf16(ahi, blo0, acc0, 0, 0, 0);
      acc0 = __builtin_amdgcn_mfma_f32_16x16x32_bf16(alo, bhi0, acc0, 0, 0, 0);
      acc1 = __builtin_amdgcn_mfma_f32_16x16x32_bf16(ahi, bhi1, acc1, 0, 0, 0);
      acc1 = __builtin_amdgcn_mfma_f32_16x16x32_bf16(ahi, blo1, acc1, 0, 0, 0);
      acc1 = __builtin_amdgcn_mfma_f32_16x16x32_bf16(alo, bhi1, acc1, 0, 0, 0);
    }
#pragma unroll
    for (int r = 0; r < 4; ++r) {
      int i = mt * 16 + qw * 4 + r;
      int j0 = ln15, j1 = 16 + ln15;
      T[i][j0] = (j0 < i) ? -bet[i] * acc0[r] : 0.f;
      T[i][j1] = (j1 < i) ? -bet[i] * acc1[r] : 0.f;
    }
  } else {
    const int mt = wv - 2;
    const long qoff = (long)(b * SEQ + l0 + mt * 16 + ln15) * DMODEL + h * DHEAD;
    __hip_bfloat16* qdst = qpk + ((long)bh * SEQ + l0 + mt * 16 + ln15) * DHEAD;
    f4v acc0 = (f4v){0.f, 0.f, 0.f, 0.f};
    f4v acc1 = (f4v){0.f, 0.f, 0.f, 0.f};
#pragma unroll
    for (int ks = 0; ks < 8; ++ks) {
      float4 q0 = *(const float4*)(qn + qoff + ks * 32 + qw * 8);
      float4 q1 = *(const float4*)(qn + qoff + ks * 32 + qw * 8 + 4);
      float a8[8] = {q0.x, q0.y, q0.z, q0.w, q1.x, q1.y, q1.z, q1.w};
      s8v ahi, alo;
#pragma unroll
      for (int j = 0; j < 8; ++j) {
        unsigned short hb = f2b(a8[j]);
        ahi[j] = (short)hb;
        alo[j] = (short)f2b(a8[j] - b2f(hb));
      }
      *(s8v*)(qdst + ks * 32 + qw * 8) = ahi;
      s8v bhi0 = *(const s8v*)&khi[ln15 * 264 + ks * 32 + qw * 8];
      s8v blo0 = *(const s8v*)&klo[ln15 * 264 + ks * 32 + qw * 8];
      s8v bhi1 = *(const s8v*)&khi[(16 + ln15) * 264 + ks * 32 + qw * 8];
      s8v blo1 = *(const s8v*)&klo[(16 + ln15) * 264 + ks * 32 + qw * 8];
      acc0 = __builtin_amdgcn_mfma_f32_16x16x32_bf16(ahi, bhi0, acc0, 0, 0, 0);
      acc0 = __builtin_amdgcn_mfma_f32_16x16x32_bf16(ahi, blo0, acc0, 0, 0, 0);
      acc0 = __builtin_amdgcn_mfma_f32_16x16x32_bf16(alo, bhi0, acc0, 0, 0, 0);
      acc1 = __builtin_amdgcn_mfma_f32_16x16x32_bf16(ahi, bhi1, acc1, 0, 0, 0);
      acc1 = __builtin_amdgcn_mfma_f32_16x16x32_bf16(ahi, blo1, acc1, 0, 0, 0);
      acc1 = __builtin_amdgcn_mfma_f32_16x16x32_bf16(alo, bhi1, acc1, 0, 0, 0);
    }
    long abase = ((long)bh * NCHUNK + c) * 1024;
#pragma unroll
    for (int r = 0; r < 4; ++r) {
      int i = mt * 16 + qw * 4 + r;
      int j0 = ln15, j1 = 16 + ln15;
      attnb16[abase + i * 32 + j0] = __float2bfloat16(j0 <= i ? acc0[r] : 0.f);
      attnb16[abase + i * 32 + j1] = __float2bfloat16(j1 <= i ? acc1[r] : 0.f);
    }
  }
  __syncthreads();

  if (t < 32) {
    const int l = t;
    for (int i = 1; i < 32; ++i) {
      float s = 0.f;
      for (int j = 0; j < i; ++j) s = fmaf(T[i][j], T[j][l], s);
      T[i][l] += s;
    }
    for (int i = 0; i < 32; ++i) {
      float val = T[i][l] + (i == l ? 1.f : 0.f);
      T[i][l] = val * bet[l];
    }
  }
  __syncthreads();

  {
    const int d = t;
    float acc[32];
#pragma unroll
    for (int i = 0; i < 32; ++i) acc[i] = 0.f;
    for (int j = 0; j < 32; ++j) {
      float vv = v[((long)(b * SEQ + l0 + j)) * DMODEL + h * DHEAD + d];
#pragma unroll
      for (int i = 0; i < 32; ++i) acc[i] = fmaf(T[i][j], vv, acc[i]);
    }
    long ubase = ((long)bh * SEQ + l0) * DHEAD + d;
#pragma unroll
    for (int i = 0; i < 32; ++i) u[ubase + (long)i * DHEAD] = acc[i];
#pragma unroll
    for (int i = 0; i < 32; ++i) acc[i] = 0.f;
    for (int j = 0; j < 32; ++j) {
      float kv = b2f((unsigned short)khi[j * 264 + d]) + b2f((unsigned short)klo[j * 264 + d]);
#pragma unroll
      for (int i = 0; i < 32; ++i) acc[i] = fmaf(T[i][j], kv, acc[i]);
    }
#pragma unroll
    for (int i = 0; i < 32; ++i) wb16[ubase + (long)i * DHEAD] = __float2bfloat16(acc[i]);
  }

  {
    const int s = t;
    unsigned short* kb = (unsigned short*)kTb16 + ((long)bh * NCHUNK + c) * 8192 + (long)s * 32;
#pragma unroll
    for (int i4 = 0; i4 < 8; ++i4) {
      ushort4 pk;
      pk.x = (unsigned short)khi[(i4 * 4 + 0) * 264 + s];
      pk.y = (unsigned short)khi[(i4 * 4 + 1) * 264 + s];
      pk.z = (unsigned short)khi[(i4 * 4 + 2) * 264 + s];
      pk.w = (unsigned short)khi[(i4 * 4 + 3) * 264 + s];
      *(ushort4*)(kb + i4 * 4) = pk;
    }
  }
}

/* ---------- phase B v5 (proven 157us): 128 single-wave blocks; wave-private
   LDS for S^T / u2^T re-layouts ordered by lgkmcnt only; no barriers. ---------- */
__global__ __launch_bounds__(64, 1) void phaseB(
    const __hip_bfloat16* __restrict__ qpk, const __hip_bfloat16* __restrict__ wb,
    const __hip_bfloat16* __restrict__ kTb, const __hip_bfloat16* __restrict__ attnb,
    const float* __restrict__ u, float* __restrict__ delta) {
  __shared__ __align__(16) short St[16 * 264];
  __shared__ __align__(16) short Ut[16 * 40];
  const int bid = blockIdx.x;
  const int slice = bid & 15;
  const int bh = bid >> 4;
  const int d0 = slice * 16;
  const int t = threadIdx.x; /* 0..63 */
  const int ln15 = t & 15;
  const int qw = t >> 4;

  const short* wbase = (const short*)wb + (long)bh * SEQ * 256;
  const short* qbase = (const short*)qpk + (long)bh * SEQ * 256;
  const short* kTbase = (const short*)kTb + (long)bh * NCHUNK * 8192;
  const short* atbase = (const short*)attnb + (long)bh * NCHUNK * 1024;
  const float* ubase = u + (long)bh * SEQ * 256;
  float* dbase = delta + (long)bh * SEQ * 256;

  f4v Sacc[16];
#pragma unroll
  for (int kt = 0; kt < 16; ++kt) Sacc[kt] = (f4v){0.f, 0.f, 0.f, 0.f};

  s8v wA[2][8], kA[16], atv[2];
  float uf[2][4];
  {
#pragma unroll
    for (int mt = 0; mt < 2; ++mt)
#pragma unroll
      for (int ks = 0; ks < 8; ++ks)
        wA[mt][ks] = *(const s8v*)(wbase + (long)(mt * 16 + ln15) * 256 + ks * 32 + qw * 8);
#pragma unroll
    for (int kt = 0; kt < 16; ++kt)
      kA[kt] = *(const s8v*)(kTbase + (kt * 16 + ln15) * 32 + qw * 8);
#pragma unroll
    for (int mt = 0; mt < 2; ++mt) {
      atv[mt] = *(const s8v*)(atbase + (mt * 16 + ln15) * 32 + qw * 8);
#pragma unroll
      for (int r = 0; r < 4; ++r)
        uf[mt][r] = ubase[(long)(mt * 16 + qw * 4 + r) * 256 + d0 + ln15];
    }
  }

  for (int c = 0; c < NCHUNK; ++c) {
    const int l0 = c * 32;

    s8v qA[2][8];
#pragma unroll
    for (int mt = 0; mt < 2; ++mt)
#pragma unroll
      for (int ks = 0; ks < 8; ++ks)
        qA[mt][ks] = *(const s8v*)(qbase + (long)(l0 + mt * 16 + ln15) * 256 + ks * 32 + qw * 8);

    /* (1) pack S^T into wave-private LDS */
#pragma unroll
    for (int kt = 0; kt < 16; ++kt) {
      ushort4 pk;
      pk.x = f2b(Sacc[kt][0]); pk.y = f2b(Sacc[kt][1]);
      pk.z = f2b(Sacc[kt][2]); pk.w = f2b(Sacc[kt][3]);
      *(ushort4*)&St[ln15 * 264 + kt * 16 + qw * 4] = pk;
    }
    asm volatile("s_waitcnt lgkmcnt(0)" ::: "memory");
    s8v bS[8];
#pragma unroll
    for (int ks = 0; ks < 8; ++ks)
      bS[ks] = *(const s8v*)&St[ln15 * 264 + ks * 32 + qw * 8];

    /* (2) dw = w @ S */
    f4v dwa0 = (f4v){0.f,0.f,0.f,0.f}, dwb0 = (f4v){0.f,0.f,0.f,0.f};
    f4v dwa1 = (f4v){0.f,0.f,0.f,0.f}, dwb1 = (f4v){0.f,0.f,0.f,0.f};
#pragma unroll
    for (int ks = 0; ks < 4; ++ks) {
      dwa0 = __builtin_amdgcn_mfma_f32_16x16x32_bf16(wA[0][ks], bS[ks], dwa0, 0, 0, 0);
      dwa1 = __builtin_amdgcn_mfma_f32_16x16x32_bf16(wA[1][ks], bS[ks], dwa1, 0, 0, 0);
      dwb0 = __builtin_amdgcn_mfma_f32_16x16x32_bf16(wA[0][ks + 4], bS[ks + 4], dwb0, 0, 0, 0);
      dwb1 = __builtin_amdgcn_mfma_f32_16x16x32_bf16(wA[1][ks + 4], bS[ks + 4], dwb1, 0, 0, 0);
    }
    float u2a[4], u2b[4];
#pragma unroll
    for (int r = 0; r < 4; ++r) {
      u2a[r] = uf[0][r] - (dwa0[r] + dwb0[r]);
      u2b[r] = uf[1][r] - (dwa1[r] + dwb1[r]);
    }
    {
      ushort4 pa, pb;
      pa.x = f2b(u2a[0]); pa.y = f2b(u2a[1]); pa.z = f2b(u2a[2]); pa.w = f2b(u2a[3]);
      pb.x = f2b(u2b[0]); pb.y = f2b(u2b[1]); pb.z = f2b(u2b[2]); pb.w = f2b(u2b[3]);
      *(ushort4*)&Ut[(d0 * 0 + (t & 15)) * 40 + qw * 4] = pa;
      *(ushort4*)&Ut[(t & 15) * 40 + 16 + qw * 4] = pb;
    }
    asm volatile("s_waitcnt lgkmcnt(0)" ::: "memory");
    s8v bu = *(const s8v*)&Ut[ln15 * 40 + qw * 8];

    /* (3) attn part of o */
    f4v oA0 = __builtin_amdgcn_mfma_f32_16x16x32_bf16(atv[0], bu, (f4v){0.f,0.f,0.f,0.f}, 0, 0, 0);
    f4v oA1 = __builtin_amdgcn_mfma_f32_16x16x32_bf16(atv[1], bu, (f4v){0.f,0.f,0.f,0.f}, 0, 0, 0);

    /* (4) recurrence: S += kT @ u2 */
#pragma unroll
    for (int kt = 0; kt < 16; ++kt)
      Sacc[kt] = __builtin_amdgcn_mfma_f32_16x16x32_bf16(kA[kt], bu, Sacc[kt], 0, 0, 0);

    /* (5) prefetch chunk c+1 operands */
    if (c + 1 < NCHUNK) {
      const int ln = l0 + 32;
#pragma unroll
      for (int mt = 0; mt < 2; ++mt)
#pragma unroll
        for (int ks = 0; ks < 8; ++ks)
          wA[mt][ks] = *(const s8v*)(wbase + (long)(ln + mt * 16 + ln15) * 256 + ks * 32 + qw * 8);
#pragma unroll
      for (int kt = 0; kt < 16; ++kt)
        kA[kt] = *(const s8v*)(kTbase + (long)(c + 1) * 8192 + (kt * 16 + ln15) * 32 + qw * 8);
#pragma unroll
      for (int mt = 0; mt < 2; ++mt) {
        atv[mt] = *(const s8v*)(atbase + (long)(c + 1) * 1024 + (mt * 16 + ln15) * 32 + qw * 8);
#pragma unroll
        for (int r = 0; r < 4; ++r)
          uf[mt][r] = ubase[(long)(ln + mt * 16 + qw * 4 + r) * 256 + d0 + ln15];
      }
    }

    /* (6) o += q @ S (pre-update S, from bS regs) */
    f4v oB0 = (f4v){0.f,0.f,0.f,0.f}, oB1 = (f4v){0.f,0.f,0.f,0.f};
#pragma unroll
    for (int ks = 0; ks < 4; ++ks) {
      oA0 = __builtin_amdgcn_mfma_f32_16x16x32_bf16(qA[0][ks], bS[ks], oA0, 0, 0, 0);
      oA1 = __builtin_amdgcn_mfma_f32_16x16x32_bf16(qA[1][ks], bS[ks], oA1, 0, 0, 0);
      oB0 = __builtin_amdgcn_mfma_f32_16x16x32_bf16(qA[0][ks + 4], bS[ks + 4], oB0, 0, 0, 0);
      oB1 = __builtin_amdgcn_mfma_f32_16x16x32_bf16(qA[1][ks + 4], bS[ks + 4], oB1, 0, 0, 0);
    }
#pragma unroll
    for (int r = 0; r < 4; ++r) {
      dbase[(long)(l0 + qw * 4 + r) * 256 + d0 + ln15] = oA0[r] + oB0[r];
      dbase[(long)(l0 + 16 + qw * 4 + r) * 256 + d0 + ln15] = oA1[r] + oB1[r];
    }
  }
}

/* ---------- FIR v3: LDS-tiled, 32 rows x 128 ch per block, sliding window.
   Global traffic 31x -> ~2x. FMA order matches v2 bit-for-bit. ---------- */
__global__ __launch_bounds__(256) void fir_tiled(
    const float* __restrict__ v, const float* __restrict__ fsT,
    const float* __restrict__ flT, float* __restrict__ fs, float* __restrict__ fl) {
  __shared__ float vt[62][128];
  const int tile = blockIdx.x;        /* 0..255 over ROWS/32 */
  const int cg0 = blockIdx.y * 128;   /* channel group */
  const int t = threadIdx.x;
  const int l0 = (tile * 32) & (SEQ - 1);
  const long grow0 = (long)tile * 32;
  /* stage 62 rows x 128 ch as float4 */
#pragma unroll
  for (int i = 0; i < 8; ++i) {
    int e = t + 256 * i;
    int r = e >> 5, c4 = (e & 31) * 4;
    if (r < 62) {
      int lr = l0 - 30 + r;
      float4 val = (lr >= 0)
          ? *(const float4*)(v + (grow0 - 30 + r) * DMODEL + cg0 + c4)
          : make_float4(0.f, 0.f, 0.f, 0.f);
      *(float4*)&vt[r][c4] = val;
    }
  }
  const int c = t & 127;
  const int half = t >> 7;
  float wl[31], wsv[3];
#pragma unroll
  for (int j = 0; j < 31; ++j) wl[j] = flT[j * DMODEL + cg0 + c];
#pragma unroll
  for (int j = 0; j < 3; ++j) wsv[j] = fsT[j * DMODEL + cg0 + c];
  __syncthreads();
  const int rb = half * 16;
  float w[31];
#pragma unroll
  for (int j = 0; j < 31; ++j) w[j] = vt[rb + j][c];
#pragma unroll
  for (int i = 0; i < 16; ++i) {
    float al = 0.f;
#pragma unroll
    for (int j = 0; j < 31; ++j) al = fmaf(wl[j], w[j], al);
    float as = fmaf(wsv[2], w[30], fmaf(wsv[1], w[29], fmaf(wsv[0], w[28], 0.f)));
    long orow = grow0 + rb + i;
    fl[orow * DMODEL + cg0 + c] = al;
    fs[orow * DMODEL + cg0 + c] = as;
    if (i < 15) {
#pragma unroll
      for (int j = 0; j < 30; ++j) w[j] = w[j + 1];
      w[30] = vt[rb + i + 31][c];
    }
  }
}

/* ---------- logits from bf16 hmid ; p = softmax(logits/tau)*0.925+0.025 ---------- */
__global__ __launch_bounds__(256) void router_logits(
    const __hip_bfloat16* __restrict__ hmid, const float* __restrict__ Wr2,
    const float* __restrict__ br2, const float* __restrict__ ltg, float* __restrict__ p) {
  const int row = blockIdx.x;
  const int t = threadIdx.x;
  float acc[12];
#pragma unroll
  for (int j = 0; j < 12; ++j) acc[j] = 0.f;
  const __hip_bfloat16* hr = hmid + (long)row * 2048;
  for (int k = t; k < 2048; k += 256) {
    float hv = __bfloat162float(hr[k]);
    const float* wr = Wr2 + k * 12;
#pragma unroll
    for (int j = 0; j < 12; ++j) acc[j] = fmaf(hv, wr[j], acc[j]);
  }
#pragma unroll
  for (int m = 1; m < 64; m <<= 1)
#pragma unroll
    for (int j = 0; j < 12; ++j) acc[j] += __shfl_xor(acc[j], m);
  __shared__ float red[4][12];
  if ((t & 63) == 0) {
    int wv = t >> 6;
#pragma unroll
    for (int j = 0; j < 12; ++j) red[wv][j] = acc[j];
  }
  __syncthreads();
  if (t < 4) {
    const int h = t;
    float l3[3];
#pragma unroll
    for (int j = 0; j < 3; ++j) {
      int col = h * 3 + j;
      l3[j] = red[0][col] + red[1][col] + red[2][col] + red[3][col] + br2[col];
    }
    float inv_tau = expf(-ltg[h >> 1]);
    float y0 = l3[0] * inv_tau, y1 = l3[1] * inv_tau, y2 = l3[2] * inv_tau;
    float mx = fmaxf(y0, fmaxf(y1, y2));
    float e0 = expf(y0 - mx), e1 = expf(y1 - mx), e2 = expf(y2 - mx);
    float inv = 1.f / (e0 + e1 + e2);
    p[(long)row * 12 + h * 3 + 0] = e0 * inv * 0.925f + 0.025f;
    p[(long)row * 12 + h * 3 + 1] = e1 * inv * 0.925f + 0.025f;
    p[(long)row * 12 + h * 3 + 2] = e2 * inv * 0.925f + 0.025f;
  }
}

/* ---------- mixture + identity + RMS norm -> bf16 out ---------- */
__global__ __launch_bounds__(256) void omix(
    const float* __restrict__ fs, const float* __restrict__ fl,
    const float* __restrict__ dl, const float* __restrict__ vh,
    const float* __restrict__ p, const float* __restrict__ idsc,
    const float* __restrict__ onw, __hip_bfloat16* __restrict__ o) {
  const int row = blockIdx.x;
  const int b = row >> 12;
  const int l = row & (SEQ - 1);
  const int t = threadIdx.x;
  const int h = t >> 6;
  const int lane = t & 63;
  const long base = (long)row * DMODEL + h * DHEAD + lane * 4;
  const long dbase = ((long)(b * NH + h) * SEQ + l) * DHEAD + lane * 4;
  float p0 = p[(long)row * 12 + h * 3 + 0];
  float p1 = p[(long)row * 12 + h * 3 + 1];
  float p2 = p[(long)row * 12 + h * 3 + 2];
  float idv = idsc[(long)row * NH + h];
  float4 a = *(const float4*)(fs + base);
  float4 bq = *(const float4*)(fl + base);
  float4 cq = *(const float4*)(dl + dbase);
  float4 vv = *(const float4*)(vh + base);
  float4 ov;
  ov.x = p0 * a.x + p1 * bq.x + p2 * cq.x + idv * vv.x;
  ov.y = p0 * a.y + p1 * bq.y + p2 * cq.y + idv * vv.y;
  ov.z = p0 * a.z + p1 * bq.z + p2 * cq.z + idv * vv.z;
  ov.w = p0 * a.w + p1 * bq.w + p2 * cq.w + idv * vv.w;
  float ss = ov.x * ov.x + ov.y * ov.y + ov.z * ov.z + ov.w * ov.w;
#pragma unroll
  for (int m = 1; m < 64; m <<= 1) ss += __shfl_xor(ss, m);
  float rms = rsqrtf(ss * (1.f / 256.f) + 1e-5f);
  float4 wn = *(const float4*)(onw + lane * 4);
  __hip_bfloat16 tmp[4] = {__float2bfloat16(ov.x * rms * wn.x),
                           __float2bfloat16(ov.y * rms * wn.y),
                           __float2bfloat16(ov.z * rms * wn.z),
                           __float2bfloat16(ov.w * rms * wn.w)};
  *(ushort4*)(o + base) = *(ushort4*)tmp;
}

extern "C" void kernel_launch(void* const* d_in, const int* in_sizes, int n_in,
                              void* d_out, int out_size, void* d_ws, size_t ws_size,
                              hipStream_t stream) {
  const float* x = (const float*)d_in[0];
  const float* Wq = (const float*)d_in[1];
  const float* Wk = (const float*)d_in[2];
  const float* Wv = (const float*)d_in[3];
  const float* Wb = (const float*)d_in[4];
  const float* conv_q = (const float*)d_in[5];
  const float* conv_k = (const float*)d_in[6];
  const float* conv_v = (const float*)d_in[7];
  const float* fir_s = (const float*)d_in[8];
  const float* fir_l = (const float*)d_in[9];
  const float* alpha_id = (const float*)d_in[10];
  const float* Wid = (const float*)d_in[11];
  const float* bidp = (const float*)d_in[12];
  const float* Wr1 = (const float*)d_in[13];
  const float* br1 = (const float*)d_in[14];
  const float* Wr2 = (const float*)d_in[15];
  const float* br2 = (const float*)d_in[16];
  const float* ltg = (const float*)d_in[17];
  const float* onw = (const float*)d_in[19];
  const float* Wo = (const float*)d_in[20];

  float* ws = (float*)d_ws;
  float* pre = ws + 0;
  float* ubuf = ws + 8388608;
  float* wbuf = ws + 16777216;
  float* attnbuf = ws + 25165824;
  float* qbuf = ws + 26214400;
  float* kbuf = ws + 34603008;
  float* vbuf = ws + 42991616;
  float* betabuf = ws + 51380224;
  float* idscbuf = ws + 51412992;
  float* pbuf = ws + 51445760;
  float* flTb = ws + 51544064;  /* 31*1024 */
  float* fsTb = ws + 51575808;  /* 3*1024, end 51578880 (~206.3 MB) */
  float* deltabuf = ubuf;
  __hip_bfloat16* xb = (__hip_bfloat16*)ubuf;
  __hip_bfloat16* Wqt = (__hip_bfloat16*)(wbuf);
  __hip_bfloat16* Wkt = (__hip_bfloat16*)(wbuf + 524288);
  __hip_bfloat16* Wvt = (__hip_bfloat16*)(wbuf + 1048576);
  __hip_bfloat16* wb16 = (__hip_bfloat16*)wbuf;
  __hip_bfloat16* kTb16 = (__hip_bfloat16*)wbuf + 8388608;
  __hip_bfloat16* attnb16 = (__hip_bfloat16*)attnbuf;
  __hip_bfloat16* qpk16 = (__hip_bfloat16*)pre;
  __hip_bfloat16* rinb = (__hip_bfloat16*)(wbuf);
  __hip_bfloat16* Wr1t = (__hip_bfloat16*)(wbuf + 4325376);
  __hip_bfloat16* Wot = (__hip_bfloat16*)(wbuf + 5406720);
  __hip_bfloat16* omixb = (__hip_bfloat16*)(wbuf);
  __hip_bfloat16* hmid = (__hip_bfloat16*)pre;
  float* fsb = qbuf;
  float* flb = kbuf;

  dim3 blk(256);
  head_fused<<<dim3(11298), blk, 0, stream>>>(x, xb, Wb, Wid, alpha_id, bidp,
      betabuf, idscbuf, Wq, Wqt, Wk, Wkt, Wv, Wvt, fir_s, fir_l, fsTb, flTb);
  gemm_bf16<0, false><<<dim3(8, 64), blk, 0, stream>>>(xb, Wqt, nullptr, pre, ROWS, 1024, 1024);
  conv_silu<1><<<dim3(ROWS), blk, 0, stream>>>(pre, conv_q, qbuf);
  gemm_bf16<0, false><<<dim3(8, 64), blk, 0, stream>>>(xb, Wkt, nullptr, pre, ROWS, 1024, 1024);
  conv_silu<1><<<dim3(ROWS), blk, 0, stream>>>(pre, conv_k, kbuf);
  gemm_bf16<0, false><<<dim3(8, 64), blk, 0, stream>>>(xb, Wvt, nullptr, pre, ROWS, 1024, 1024);
  conv_silu<0><<<dim3(ROWS), blk, 0, stream>>>(pre, conv_v, vbuf);
  phaseA<<<dim3(BATCH * NH * NCHUNK), blk, 0, stream>>>(qbuf, kbuf, vbuf, betabuf, ubuf, wb16, kTb16, attnb16, qpk16);
  phaseB<<<dim3(BATCH * NH * 16), dim3(64), 0, stream>>>(qpk16, wb16, kTb16, attnb16, ubuf, deltabuf);
  fir_tiled<<<dim3(ROWS / 32, 8), blk, 0, stream>>>(vbuf, fsTb, flTb, fsb, flb);
  stats_tcast<<<dim3(11328), blk, 0, stream>>>(x, fsb, flb, deltabuf, rinb, Wr1, Wr1t, Wo, Wot);
  gemm_bf16<1, true><<<dim3(16, 64), blk, 0, stream>>>(rinb, Wr1t, br1, hmid, ROWS, 2048, 1056);
  router_logits<<<dim3(ROWS), blk, 0, stream>>>(hmid, Wr2, br2, ltg, pbuf);
  omix<<<dim3(ROWS), blk, 0, stream>>>(fsb, flb, deltabuf, vbuf, pbuf, idscbuf, onw, omixb);
  gemm_bf16<0, false><<<dim3(8, 64), blk, 0, stream>>>(omixb, Wot, nullptr, d_out, ROWS, 1024, 1024);
}